// Round 1
// baseline (3522.279 us; speedup 1.0000x reference)
//
#include <hip/hip_runtime.h>
#include <math.h>

#define B_ 4
#define N_ 1024
#define C_ 1024
#define NH_ 16
#define HD_ 64
#define PP_ 128
#define AR 8

__device__ __forceinline__ float gelu_f(float x) {
    return 0.5f * x * (1.0f + erff(x * 0.70710678118654752f));
}

// ---------------- generic tiled GEMM: Co[M,Nc] = A[M,K]@Bw[K,Nc] (+bias)(gelu?)(+resid) ----
__global__ __launch_bounds__(256) void gemm_k(
    const float* __restrict__ A, const float* __restrict__ Bw,
    const float* __restrict__ bias, const float* __restrict__ resid,
    float* __restrict__ Co, int M, int K, int Nc, int act_gelu)
{
    __shared__ float As[16][68];
    __shared__ float Bs[16][68];
    const int t = threadIdx.x;
    const int tx = t & 15, ty = t >> 4;
    const int row0 = blockIdx.y * 64, col0 = blockIdx.x * 64;
    float acc[4][4] = {};
    const int mload = t >> 2;          // 0..63
    const int kload = (t & 3) * 4;     // 0,4,8,12
    const int kbrow = t >> 4;          // 0..15
    const int nload = (t & 15) * 4;    // 0..60
    for (int k0 = 0; k0 < K; k0 += 16) {
        float4 av = *reinterpret_cast<const float4*>(A + (size_t)(row0 + mload) * K + k0 + kload);
        As[kload + 0][mload] = av.x;
        As[kload + 1][mload] = av.y;
        As[kload + 2][mload] = av.z;
        As[kload + 3][mload] = av.w;
        float4 bv = *reinterpret_cast<const float4*>(Bw + (size_t)(k0 + kbrow) * Nc + col0 + nload);
        Bs[kbrow][nload + 0] = bv.x;
        Bs[kbrow][nload + 1] = bv.y;
        Bs[kbrow][nload + 2] = bv.z;
        Bs[kbrow][nload + 3] = bv.w;
        __syncthreads();
        #pragma unroll
        for (int k = 0; k < 16; ++k) {
            float a[4], b[4];
            #pragma unroll
            for (int i = 0; i < 4; ++i) a[i] = As[k][ty * 4 + i];
            #pragma unroll
            for (int j = 0; j < 4; ++j) b[j] = Bs[k][tx * 4 + j];
            #pragma unroll
            for (int i = 0; i < 4; ++i)
                #pragma unroll
                for (int j = 0; j < 4; ++j)
                    acc[i][j] = fmaf(a[i], b[j], acc[i][j]);
        }
        __syncthreads();
    }
    #pragma unroll
    for (int i = 0; i < 4; ++i) {
        const int r = row0 + ty * 4 + i;
        const int c = col0 + tx * 4;
        float4 o;
        float* po = &o.x;
        #pragma unroll
        for (int j = 0; j < 4; ++j) {
            float v = acc[i][j];
            if (bias) v += bias[c + j];
            if (act_gelu) v = gelu_f(v);
            if (resid) v += resid[(size_t)r * Nc + c + j];
            po[j] = v;
        }
        *reinterpret_cast<float4*>(Co + (size_t)r * Nc + c) = o;
    }
}

// ---------------- in-place RoPE on one tensor region (per-head, pos = n) ----------------
__global__ __launch_bounds__(256) void rope_k(float* __restrict__ buf, int row_stride, int col_off)
{
    int g = blockIdx.x * 256 + threadIdx.x;
    if (g >= B_ * N_ * NH_ * 32) return;
    const int i = g & 31;
    const int h = (g >> 5) & (NH_ - 1);
    const int rown = g >> 9;              // b*N + n
    const int n = rown & (N_ - 1);
    const float inv = powf(10000.0f, -(float)(2 * i) / 64.0f);
    const float ang = (float)n * inv;
    const float s = sinf(ang), c = cosf(ang);
    size_t base = (size_t)rown * row_stride + col_off + h * 64 + 2 * i;
    const float x1 = buf[base], x2 = buf[base + 1];
    buf[base]     = x1 * c - x2 * s;
    buf[base + 1] = x2 * c + x1 * s;
}

// ---------------- self attention: q,k,v packed in qkv (B,N,3C), rel bias from table ------
__global__ __launch_bounds__(256) void self_attn_k(
    const float* __restrict__ qkv, const float* __restrict__ rel_table,
    float* __restrict__ sa)
{
    __shared__ float sc[AR][1024];
    __shared__ float qs[AR][65];
    __shared__ float ks[64][65];
    __shared__ float rowsum[AR];
    const int b = blockIdx.z, h = blockIdx.y, r0 = blockIdx.x * AR;
    const int t = threadIdx.x;
    const size_t base = (size_t)b * N_ * 3072;
    for (int i = t; i < AR * 64; i += 256) {
        int r = i >> 6, d = i & 63;
        qs[r][d] = qkv[base + (size_t)(r0 + r) * 3072 + h * 64 + d];
    }
    const int col = t & 63;
    const int grp = t >> 6;   // 0..3, handles rows grp and grp+4
    const float scale = 0.125f;
    for (int mt = 0; mt < 16; ++mt) {
        __syncthreads();
        for (int i = t; i < 64 * 64; i += 256) {
            int m = i >> 6, d = i & 63;
            ks[m][d] = qkv[base + (size_t)(mt * 64 + m) * 3072 + C_ + h * 64 + d];
        }
        __syncthreads();
        const int mg = mt * 64 + col;
        const int ym = mg >> 5, xm = mg & 31;
        #pragma unroll
        for (int rr = 0; rr < 2; ++rr) {
            const int r = grp + rr * 4;
            float acc = 0.f;
            #pragma unroll 8
            for (int d = 0; d < 64; ++d)
                acc = fmaf(qs[r][d], ks[col][d], acc);
            const int ng = r0 + r;
            const int yn = ng >> 5, xn = ng & 31;
            const int idx = (yn - ym + 31) * 63 + (xn - xm + 31);
            sc[r][mg] = acc * scale + rel_table[idx * NH_ + h];
        }
    }
    __syncthreads();
    {   // softmax: 32 threads per row
        const int r = t >> 5, l = t & 31;
        float mx = -1e30f;
        for (int i = l; i < 1024; i += 32) mx = fmaxf(mx, sc[r][i]);
        #pragma unroll
        for (int m = 16; m >= 1; m >>= 1) mx = fmaxf(mx, __shfl_xor(mx, m));
        float sum = 0.f;
        for (int i = l; i < 1024; i += 32) {
            float e = expf(sc[r][i] - mx);
            sc[r][i] = e;
            sum += e;
        }
        #pragma unroll
        for (int m = 16; m >= 1; m >>= 1) sum += __shfl_xor(sum, m);
        if (l == 0) rowsum[r] = sum;
    }
    __syncthreads();
    float accv[2] = {0.f, 0.f};
    for (int mt = 0; mt < 16; ++mt) {
        __syncthreads();
        for (int i = t; i < 64 * 64; i += 256) {
            int m = i >> 6, d = i & 63;
            ks[m][d] = qkv[base + (size_t)(mt * 64 + m) * 3072 + 2 * C_ + h * 64 + d];
        }
        __syncthreads();
        #pragma unroll
        for (int rr = 0; rr < 2; ++rr) {
            const int r = grp + rr * 4;
            float a = 0.f;
            #pragma unroll 8
            for (int m = 0; m < 64; ++m)
                a = fmaf(sc[r][mt * 64 + m], ks[m][col], a);
            accv[rr] += a;
        }
    }
    #pragma unroll
    for (int rr = 0; rr < 2; ++rr) {
        const int r = grp + rr * 4;
        sa[(size_t)(b * N_ + r0 + r) * C_ + h * 64 + col] = accv[rr] / rowsum[r];
    }
}

// ---------------- cross attention with sim/ds/gb biases ----------------
__global__ __launch_bounds__(256) void cross_attn_k(
    const float* __restrict__ cq, const float* __restrict__ ck, const float* __restrict__ cv,
    const float* __restrict__ dn, const float* __restrict__ ds, const float* __restrict__ gb,
    const float* __restrict__ rdb, float* __restrict__ co)
{
    __shared__ float sc[AR][1024];
    __shared__ float qs[AR][65];
    __shared__ float ks[64][65];
    __shared__ float dnq[AR][4];
    __shared__ float dnm[64][4];
    __shared__ float gbm[64];
    __shared__ float dsr[AR];
    __shared__ float rowsum[AR];
    const int b = blockIdx.z, h = blockIdx.y, r0 = blockIdx.x * AR;
    const int t = threadIdx.x;
    const size_t rowbase = (size_t)b * N_;
    for (int i = t; i < AR * 64; i += 256) {
        int r = i >> 6, d = i & 63;
        qs[r][d] = cq[(rowbase + r0 + r) * C_ + h * 64 + d];
    }
    if (t < AR * 4) dnq[t >> 2][t & 3] = dn[(rowbase + r0 + (t >> 2)) * 4 + (t & 3)];
    if (t < AR)     dsr[t] = 1.0f + ds[(rowbase + r0 + t) * NH_ + h];
    const float rdbh = rdb[h];
    const int col = t & 63;
    const int grp = t >> 6;
    const float scale = 0.125f;
    for (int mt = 0; mt < 16; ++mt) {
        __syncthreads();
        for (int i = t; i < 64 * 64; i += 256) {
            int m = i >> 6, d = i & 63;
            ks[m][d] = ck[(rowbase + mt * 64 + m) * C_ + h * 64 + d];
        }
        dnm[t >> 2][t & 3] = dn[(rowbase + mt * 64 + (t >> 2)) * 4 + (t & 3)];
        if (t < 64) gbm[t] = gb[(rowbase + mt * 64 + t) * NH_ + h];
        __syncthreads();
        #pragma unroll
        for (int rr = 0; rr < 2; ++rr) {
            const int r = grp + rr * 4;
            float acc = 0.f;
            #pragma unroll 8
            for (int d = 0; d < 64; ++d)
                acc = fmaf(qs[r][d], ks[col][d], acc);
            const float sim = dnq[r][0] * dnm[col][0] + dnq[r][1] * dnm[col][1]
                            + dnq[r][2] * dnm[col][2];
            sc[r][mt * 64 + col] = (acc * scale + sim * rdbh) * dsr[r] + gbm[col];
        }
    }
    __syncthreads();
    {
        const int r = t >> 5, l = t & 31;
        float mx = -1e30f;
        for (int i = l; i < 1024; i += 32) mx = fmaxf(mx, sc[r][i]);
        #pragma unroll
        for (int m = 16; m >= 1; m >>= 1) mx = fmaxf(mx, __shfl_xor(mx, m));
        float sum = 0.f;
        for (int i = l; i < 1024; i += 32) {
            float e = expf(sc[r][i] - mx);
            sc[r][i] = e;
            sum += e;
        }
        #pragma unroll
        for (int m = 16; m >= 1; m >>= 1) sum += __shfl_xor(sum, m);
        if (l == 0) rowsum[r] = sum;
    }
    __syncthreads();
    float accv[2] = {0.f, 0.f};
    for (int mt = 0; mt < 16; ++mt) {
        __syncthreads();
        for (int i = t; i < 64 * 64; i += 256) {
            int m = i >> 6, d = i & 63;
            ks[m][d] = cv[(rowbase + mt * 64 + m) * C_ + h * 64 + d];
        }
        __syncthreads();
        #pragma unroll
        for (int rr = 0; rr < 2; ++rr) {
            const int r = grp + rr * 4;
            float a = 0.f;
            #pragma unroll 8
            for (int m = 0; m < 64; ++m)
                a = fmaf(sc[r][mt * 64 + m], ks[m][col], a);
            accv[rr] += a;
        }
    }
    #pragma unroll
    for (int rr = 0; rr < 2; ++rr) {
        const int r = grp + rr * 4;
        co[(rowbase + r0 + r) * C_ + h * 64 + col] = accv[rr] / rowsum[r];
    }
}

// ---------------- plucker MLP (pp), ds MLP, dn normalize — one block per row -------------
__global__ __launch_bounds__(256) void plucker_k(
    const float* __restrict__ pl,
    const float* __restrict__ w1, const float* __restrict__ b1,
    const float* __restrict__ w2, const float* __restrict__ b2,
    const float* __restrict__ w3, const float* __restrict__ b3,
    const float* __restrict__ dw1, const float* __restrict__ db1,
    const float* __restrict__ dw2, const float* __restrict__ db2,
    float* __restrict__ pp, float* __restrict__ ds, float* __restrict__ dn)
{
    const int row = blockIdx.x;
    const int t = threadIdx.x;
    __shared__ float plr[6];
    __shared__ float h1[256];
    __shared__ float h2[128];
    __shared__ float dh[64];
    if (t < 6) plr[t] = pl[(size_t)row * 6 + t];
    __syncthreads();
    {
        float a = b1[t];
        #pragma unroll
        for (int j = 0; j < 6; ++j) a = fmaf(plr[j], w1[j * 256 + t], a);
        h1[t] = gelu_f(a);
    }
    if (t < 64) {
        float d = db1[t];
        #pragma unroll
        for (int j = 0; j < 6; ++j) d = fmaf(plr[j], dw1[j * 64 + t], d);
        dh[t] = gelu_f(d);
    }
    if (t == 0) {
        float x = plr[0], y = plr[1], z = plr[2];
        float nrm = fmaxf(sqrtf(x * x + y * y + z * z), 1e-12f);
        dn[(size_t)row * 4 + 0] = x / nrm;
        dn[(size_t)row * 4 + 1] = y / nrm;
        dn[(size_t)row * 4 + 2] = z / nrm;
        dn[(size_t)row * 4 + 3] = 0.f;
    }
    __syncthreads();
    if (t < 128) {
        float a = b2[t];
        for (int j = 0; j < 256; ++j) a = fmaf(h1[j], w2[j * 128 + t], a);
        h2[t] = gelu_f(a);
    }
    if (t < 16) {
        float d = db2[t];
        for (int j = 0; j < 64; ++j) d = fmaf(dh[j], dw2[j * 16 + t], d);
        ds[(size_t)row * 16 + t] = tanhf(d);
    }
    __syncthreads();
    if (t < 128) {
        float a = b3[t];
        for (int j = 0; j < 128; ++j) a = fmaf(h2[j], w3[j * 128 + t], a);
        pp[(size_t)row * 128 + t] = a;
    }
}

// ---------------- spatial diff features ----------------
__global__ __launch_bounds__(256) void sd_k(const float* __restrict__ pp, float* __restrict__ sd)
{
    int g = blockIdx.x * 256 + threadIdx.x;
    if (g >= B_ * N_ * PP_) return;
    const int c = g & 127;
    const int rown = g >> 7;
    const int n = rown & (N_ - 1);
    const int xx = n & 31, yy = (n >> 5) & 31;
    const float cur = pp[g];
    const float hd = (xx < 31) ? fabsf(pp[g + PP_] - cur) : 0.f;
    const float vd = (yy < 31) ? fabsf(pp[g + 32 * PP_] - cur) : 0.f;
    sd[(size_t)rown * 256 + c] = hd;
    sd[(size_t)rown * 256 + 128 + c] = vd;
}

// ---------------- gb MLP: sd(256) -> gelu(512) -> tanh(16), one block per row ------------
__global__ __launch_bounds__(256) void gb_k(
    const float* __restrict__ sd,
    const float* __restrict__ w1, const float* __restrict__ b1,
    const float* __restrict__ w2, const float* __restrict__ b2,
    float* __restrict__ gb)
{
    const int row = blockIdx.x;
    const int t = threadIdx.x;
    __shared__ float s[256];
    __shared__ float h[512];
    s[t] = sd[(size_t)row * 256 + t];
    __syncthreads();
    #pragma unroll
    for (int o = 0; o < 2; ++o) {
        const int c = t + o * 256;
        float a = b1[c];
        for (int j = 0; j < 256; ++j) a = fmaf(s[j], w1[j * 512 + c], a);
        h[c] = gelu_f(a);
    }
    __syncthreads();
    if (t < 16) {
        float a = b2[t];
        for (int j = 0; j < 512; ++j) a = fmaf(h[j], w2[j * 16 + t], a);
        gb[(size_t)row * 16 + t] = tanhf(a);
    }
}

// ---------------- concat [co_p | pp] ----------------
__global__ __launch_bounds__(256) void cat_k(
    const float* __restrict__ a, const float* __restrict__ p, float* __restrict__ o)
{
    size_t g = (size_t)blockIdx.x * 256 + threadIdx.x;
    if (g >= (size_t)4096 * 1152) return;
    const int c = (int)(g % 1152);
    const size_t r = g / 1152;
    o[g] = (c < 1024) ? a[r * 1024 + c] : p[r * 128 + (c - 1024)];
}

extern "C" void kernel_launch(void* const* d_in, const int* in_sizes, int n_in,
                              void* d_out, int out_size, void* d_ws, size_t ws_size,
                              hipStream_t stream)
{
    const float* x     = (const float*)d_in[0];
    const float* pl    = (const float*)d_in[1];
    const float* w_qkv = (const float*)d_in[2];
    const float* w_sp  = (const float*)d_in[3];
    const float* b_sp  = (const float*)d_in[4];
    const float* pl_w1 = (const float*)d_in[5];
    const float* pl_b1 = (const float*)d_in[6];
    const float* pl_w2 = (const float*)d_in[7];
    const float* pl_b2 = (const float*)d_in[8];
    const float* pl_w3 = (const float*)d_in[9];
    const float* pl_b3 = (const float*)d_in[10];
    const float* w_cq  = (const float*)d_in[11];
    const float* w_pk  = (const float*)d_in[12];
    const float* w_pv  = (const float*)d_in[13];
    const float* w_cp  = (const float*)d_in[14];
    const float* b_cp  = (const float*)d_in[15];
    const float* rdb   = (const float*)d_in[16];
    const float* ds_w1 = (const float*)d_in[17];
    const float* ds_b1 = (const float*)d_in[18];
    const float* ds_w2 = (const float*)d_in[19];
    const float* ds_b2 = (const float*)d_in[20];
    const float* gb_w1 = (const float*)d_in[21];
    const float* gb_b1 = (const float*)d_in[22];
    const float* gb_w2 = (const float*)d_in[23];
    const float* gb_b2 = (const float*)d_in[24];
    const float* rel_t = (const float*)d_in[25];
    const float* gfw1  = (const float*)d_in[26];
    const float* gfb1  = (const float*)d_in[27];
    const float* gfw2  = (const float*)d_in[28];
    const float* gfb2  = (const float*)d_in[29];

    float* ws  = (float*)d_ws;
    float* out = (float*)d_out;

    // workspace layout (floats); peak 31,604,736 floats = 126.4 MB
    float* qkv = ws;                    // 12,582,912 (B,N,3C); dead after self_attn
    float* cqb = ws;                    //  4,194,304 (reuses qkv region)
    float* ckb = ws + 4194304;          //  4,194,304
    float* cvb = ws + 8388608;          //  4,194,304
    float* sa  = ws + 12582912;         //  4,194,304 ; later co
    float* sap = ws + 16777216;         //  4,194,304 ; later co_p
    float* pp  = ws + 20971520;         //    524,288
    float* sdb = ws + 21495808;         //  1,048,576
    float* dsb = ws + 22544384;         //     65,536
    float* dnb = ws + 22609920;         //     16,384
    float* gbb = ws + 22626304;         //     65,536
    float* cat = ws + 22691840;         //  4,718,592
    float* hid = ws + 27410432;         //  4,194,304

    const dim3 blk(256);
    const int rope_blocks = (B_ * N_ * NH_ * 32 + 255) / 256;

    // 1. qkv = x @ w_qkv
    gemm_k<<<dim3(3072 / 64, 4096 / 64), blk, 0, stream>>>(x, w_qkv, nullptr, nullptr, qkv, 4096, 1024, 3072, 0);
    // 2. rope q and k in place
    rope_k<<<rope_blocks, blk, 0, stream>>>(qkv, 3072, 0);
    rope_k<<<rope_blocks, blk, 0, stream>>>(qkv, 3072, 1024);
    // 3. self attention -> sa (B,N,C)
    self_attn_k<<<dim3(N_ / AR, NH_, B_), blk, 0, stream>>>(qkv, rel_t, sa);
    // 4. self proj
    gemm_k<<<dim3(16, 64), blk, 0, stream>>>(sa, w_sp, b_sp, nullptr, sap, 4096, 1024, 1024, 0);
    // 5. plucker MLPs (pp, ds, dn)
    plucker_k<<<4096, blk, 0, stream>>>(pl, pl_w1, pl_b1, pl_w2, pl_b2, pl_w3, pl_b3,
                                        ds_w1, ds_b1, ds_w2, ds_b2, pp, dsb, dnb);
    // 6-8. cq / ck / cv
    gemm_k<<<dim3(16, 64), blk, 0, stream>>>(sap, w_cq, nullptr, nullptr, cqb, 4096, 1024, 1024, 0);
    gemm_k<<<dim3(16, 64), blk, 0, stream>>>(pp, w_pk, nullptr, nullptr, ckb, 4096, 128, 1024, 0);
    gemm_k<<<dim3(16, 64), blk, 0, stream>>>(pp, w_pv, nullptr, nullptr, cvb, 4096, 128, 1024, 0);
    // 9. rope cq, ck
    rope_k<<<rope_blocks, blk, 0, stream>>>(cqb, 1024, 0);
    rope_k<<<rope_blocks, blk, 0, stream>>>(ckb, 1024, 0);
    // 10. spatial diffs
    sd_k<<<(B_ * N_ * PP_) / 256, blk, 0, stream>>>(pp, sdb);
    // 11. gb MLP
    gb_k<<<4096, blk, 0, stream>>>(sdb, gb_w1, gb_b1, gb_w2, gb_b2, gbb);
    // 12. cross attention -> co (reuse sa buffer)
    cross_attn_k<<<dim3(N_ / AR, NH_, B_), blk, 0, stream>>>(cqb, ckb, cvb, dnb, dsb, gbb, rdb, sa);
    // 13. cross proj -> co_p (reuse sap)
    gemm_k<<<dim3(16, 64), blk, 0, stream>>>(sa, w_cp, b_cp, nullptr, sap, 4096, 1024, 1024, 0);
    // 14. concat [co_p | pp]
    cat_k<<<(4096 * 1152 + 255) / 256, blk, 0, stream>>>(sap, pp, cat);
    // 15. gfe1 (gelu)
    gemm_k<<<dim3(16, 64), blk, 0, stream>>>(cat, gfw1, gfb1, nullptr, hid, 4096, 1152, 1024, 1);
    // 16. gfe2 + residual x -> out
    gemm_k<<<dim3(16, 64), blk, 0, stream>>>(hid, gfw2, gfb2, x, out, 4096, 1024, 1024, 0);
}

// Round 2
// 666.204 us; speedup vs baseline: 5.2871x; 5.2871x over previous
//
#include <hip/hip_runtime.h>
#include <math.h>

#define B_ 4
#define N_ 1024
#define C_ 1024
#define NH_ 16
#define HD_ 64
#define PP_ 128
#define SCALE_ 0.125f

typedef __bf16 bf16;
typedef __attribute__((ext_vector_type(8))) __bf16 bf16x8;
typedef __attribute__((ext_vector_type(4))) __bf16 bf16x4;
typedef __attribute__((ext_vector_type(4))) float f32x4;

#define MFMA_BF16(a, b, c) __builtin_amdgcn_mfma_f32_16x16x32_bf16((a), (b), (c), 0, 0, 0)

__device__ __forceinline__ float gelu_f(float x) {
    return 0.5f * x * (1.0f + erff(x * 0.70710678118654752f));
}

__device__ __forceinline__ void gload16(const void* g, void* l) {
    __builtin_amdgcn_global_load_lds(
        (const __attribute__((address_space(1))) void*)g,
        (__attribute__((address_space(3))) void*)l, 16, 0, 0);
}

// ============ transpose-cast fp32 W[K,N] -> bf16 Wt[N,K] (8 jobs) ============
struct TJobs {
    const float* src[8];
    bf16* dst[8];
    int K[8];
    int N[8];
};

__global__ __launch_bounds__(256) void tcast_k(TJobs J)
{
    const int j = blockIdx.z;
    const int Kd = J.K[j], Nd = J.N[j];
    const int n0 = blockIdx.x * 32, k0 = blockIdx.y * 32;
    if (n0 >= Nd || k0 >= Kd) return;
    __shared__ float tl[32][33];
    const int t = threadIdx.x, tx = t & 31, ty = t >> 5;
    const float* src = J.src[j];
    bf16* dst = J.dst[j];
    #pragma unroll
    for (int r = 0; r < 4; ++r) {
        int kk = ty + r * 8;
        tl[kk][tx] = src[(size_t)(k0 + kk) * Nd + n0 + tx];
    }
    __syncthreads();
    #pragma unroll
    for (int r = 0; r < 4; ++r) {
        int nn = ty + r * 8;
        dst[(size_t)(n0 + nn) * Kd + k0 + tx] = (bf16)tl[tx][nn];
    }
}

// ============ elementwise cast fp32 -> bf16 (4 at a time) ============
__global__ __launch_bounds__(256) void cast_rm(const float* __restrict__ in,
                                               bf16* __restrict__ out, int n4)
{
    int g = blockIdx.x * 256 + threadIdx.x;
    if (g >= n4) return;
    float4 v = reinterpret_cast<const float4*>(in)[g];
    bf16x4 o = {(bf16)v.x, (bf16)v.y, (bf16)v.z, (bf16)v.w};
    reinterpret_cast<bf16x4*>(out)[g] = o;
}

// ============ MFMA GEMM: C[M,N] = A[M,K] @ Bt[N,K]^T, bf16 in, fp32 acc ============
// tile 128x64, BK=32, 256 threads (4 waves, 2x2), wave = 64x32 out
__global__ __launch_bounds__(256) void gemm_m(
    const bf16* __restrict__ A, const bf16* __restrict__ Bt,
    const float* __restrict__ bias, const float* __restrict__ resid,
    float* __restrict__ outF, bf16* __restrict__ outB,
    int M, int N, int K, int act_gelu)
{
    __shared__ bf16 As[128 * 32];
    __shared__ bf16 Bs[64 * 32];
    const int t = threadIdx.x;
    const int w = t >> 6, lane = t & 63;
    const int row0 = blockIdx.y * 128, col0 = blockIdx.x * 64;
    const int wm = w >> 1, wn = w & 1;
    f32x4 acc[4][2];
    #pragma unroll
    for (int mi = 0; mi < 4; ++mi)
        #pragma unroll
        for (int ni = 0; ni < 2; ++ni)
            acc[mi][ni] = (f32x4){0.f, 0.f, 0.f, 0.f};

    for (int k0 = 0; k0 < K; k0 += 32) {
        // stage A: 128x32 bf16 = 8KB = 512 chunks of 16B; 2 rounds of 256
        #pragma unroll
        for (int r = 0; r < 2; ++r) {
            int c = r * 256 + t;
            const bf16* src = A + (size_t)(row0 + (c >> 2)) * K + k0 + (c & 3) * 8;
            bf16* dst = As + (size_t)(r * 256 + w * 64) * 8;   // wave-uniform base
            gload16(src, dst);
        }
        // stage B: 64x32 = 4KB = 256 chunks
        {
            int c = t;
            const bf16* src = Bt + (size_t)(col0 + (c >> 2)) * K + k0 + (c & 3) * 8;
            bf16* dst = Bs + (size_t)(w * 64) * 8;
            gload16(src, dst);
        }
        __syncthreads();
        bf16x8 af[4], bfv[2];
        #pragma unroll
        for (int mi = 0; mi < 4; ++mi)
            af[mi] = *reinterpret_cast<const bf16x8*>(
                As + (wm * 64 + mi * 16 + (lane & 15)) * 32 + (lane >> 4) * 8);
        #pragma unroll
        for (int ni = 0; ni < 2; ++ni)
            bfv[ni] = *reinterpret_cast<const bf16x8*>(
                Bs + (wn * 32 + ni * 16 + (lane & 15)) * 32 + (lane >> 4) * 8);
        #pragma unroll
        for (int mi = 0; mi < 4; ++mi)
            #pragma unroll
            for (int ni = 0; ni < 2; ++ni)
                acc[mi][ni] = MFMA_BF16(af[mi], bfv[ni], acc[mi][ni]);
        __syncthreads();
    }
    #pragma unroll
    for (int mi = 0; mi < 4; ++mi) {
        #pragma unroll
        for (int ni = 0; ni < 2; ++ni) {
            const int col = col0 + wn * 32 + ni * 16 + (lane & 15);
            const float bv = bias ? bias[col] : 0.f;
            #pragma unroll
            for (int j = 0; j < 4; ++j) {
                const int row = row0 + wm * 64 + mi * 16 + (lane >> 4) * 4 + j;
                float v = acc[mi][ni][j] + bv;
                if (act_gelu) v = gelu_f(v);
                if (resid) v += resid[(size_t)row * N + col];
                if (outF) outF[(size_t)row * N + col] = v;
                else outB[(size_t)row * N + col] = (bf16)v;
            }
        }
    }
}

// ============ RoPE pair (two tensors / two offsets in one launch) ============
__global__ __launch_bounds__(256) void rope_pair(float* __restrict__ p0, float* __restrict__ p1,
                                                 int stride, int off0, int off1)
{
    int g = blockIdx.x * 256 + threadIdx.x;
    if (g >= B_ * N_ * NH_ * 32) return;
    float* buf = blockIdx.y ? p1 : p0;
    const int off = blockIdx.y ? off1 : off0;
    const int i = g & 31;
    const int h = (g >> 5) & (NH_ - 1);
    const int rown = g >> 9;
    const int n = rown & (N_ - 1);
    const float inv = powf(10000.0f, -(float)(2 * i) / 64.0f);
    const float ang = (float)n * inv;
    const float s = sinf(ang), c = cosf(ang);
    size_t base = (size_t)rown * stride + off + h * 64 + 2 * i;
    const float x1 = buf[base], x2 = buf[base + 1];
    buf[base]     = x1 * c - x2 * s;
    buf[base + 1] = x2 * c + x1 * s;
}

// ============ MFMA flash self-attention ============
// block: (b,h,64 q-rows), 4 waves x 16 rows. LDS rows padded to 72 bf16 (144B).
__global__ __launch_bounds__(256) void attn_self_m(
    const float* __restrict__ qkv, const float* __restrict__ rel_table,
    bf16* __restrict__ sab)
{
    __shared__ bf16 Kt[64 * 72];
    __shared__ bf16 Vt[64 * 72];
    __shared__ bf16 Ps[64 * 72];
    const int t = threadIdx.x, w = t >> 6, lane = t & 63;
    const int b = blockIdx.z, h = blockIdx.y, r0 = blockIdx.x * 64;
    const size_t qbase = (size_t)b * N_ * 3072;

    // stage Q tile into Kt (temp), pull A-frags to regs
    for (int i = t; i < 1024; i += 256) {
        int row = i >> 4, c4 = (i & 15) * 4;
        float4 v = *reinterpret_cast<const float4*>(qkv + qbase + (size_t)(r0 + row) * 3072 + h * 64 + c4);
        *reinterpret_cast<bf16x4*>(Kt + row * 72 + c4) = (bf16x4){(bf16)v.x, (bf16)v.y, (bf16)v.z, (bf16)v.w};
    }
    __syncthreads();
    bf16x8 aq[2];
    aq[0] = *reinterpret_cast<const bf16x8*>(Kt + (w * 16 + (lane & 15)) * 72 + (lane >> 4) * 8);
    aq[1] = *reinterpret_cast<const bf16x8*>(Kt + (w * 16 + (lane & 15)) * 72 + 32 + (lane >> 4) * 8);
    __syncthreads();

    float m_run[4], l_run[4];
    f32x4 of[4];
    #pragma unroll
    for (int j = 0; j < 4; ++j) { m_run[j] = -3e38f; l_run[j] = 0.f; }
    #pragma unroll
    for (int dt = 0; dt < 4; ++dt) of[dt] = (f32x4){0.f, 0.f, 0.f, 0.f};

    const int qrow_lo = (lane >> 4) * 4;
    int yn[4], xn[4];
    #pragma unroll
    for (int j = 0; j < 4; ++j) {
        int qg = r0 + w * 16 + qrow_lo + j;
        yn[j] = qg >> 5; xn[j] = qg & 31;
    }

    for (int mt = 0; mt < 16; ++mt) {
        // stage K (row-major) and V (transposed) as bf16
        for (int i = t; i < 1024; i += 256) {
            int row = i >> 4, c4 = (i & 15) * 4;
            float4 kv = *reinterpret_cast<const float4*>(qkv + qbase + (size_t)(mt * 64 + row) * 3072 + C_ + h * 64 + c4);
            *reinterpret_cast<bf16x4*>(Kt + row * 72 + c4) = (bf16x4){(bf16)kv.x, (bf16)kv.y, (bf16)kv.z, (bf16)kv.w};
            float4 vv = *reinterpret_cast<const float4*>(qkv + qbase + (size_t)(mt * 64 + row) * 3072 + 2 * C_ + h * 64 + c4);
            Vt[(c4 + 0) * 72 + row] = (bf16)vv.x;
            Vt[(c4 + 1) * 72 + row] = (bf16)vv.y;
            Vt[(c4 + 2) * 72 + row] = (bf16)vv.z;
            Vt[(c4 + 3) * 72 + row] = (bf16)vv.w;
        }
        __syncthreads();

        // S = Q K^T (per wave: 16 rows x 64 cols)
        f32x4 sf[4];
        #pragma unroll
        for (int ct = 0; ct < 4; ++ct) {
            f32x4 a = (f32x4){0.f, 0.f, 0.f, 0.f};
            bf16x8 bk0 = *reinterpret_cast<const bf16x8*>(Kt + (ct * 16 + (lane & 15)) * 72 + (lane >> 4) * 8);
            bf16x8 bk1 = *reinterpret_cast<const bf16x8*>(Kt + (ct * 16 + (lane & 15)) * 72 + 32 + (lane >> 4) * 8);
            a = MFMA_BF16(aq[0], bk0, a);
            a = MFMA_BF16(aq[1], bk1, a);
            sf[ct] = a;
        }
        // bias + online softmax
        float p[4][4], mx[4];
        #pragma unroll
        for (int j = 0; j < 4; ++j) mx[j] = -3e38f;
        #pragma unroll
        for (int ct = 0; ct < 4; ++ct) {
            const int mg = mt * 64 + ct * 16 + (lane & 15);
            const int ym = mg >> 5, xm = mg & 31;
            #pragma unroll
            for (int j = 0; j < 4; ++j) {
                float s = sf[ct][j] * SCALE_ + rel_table[(size_t)((yn[j] - ym + 31) * 63 + (xn[j] - xm + 31)) * NH_ + h];
                p[ct][j] = s;
                mx[j] = fmaxf(mx[j], s);
            }
        }
        #pragma unroll
        for (int d = 1; d < 16; d <<= 1)
            #pragma unroll
            for (int j = 0; j < 4; ++j) mx[j] = fmaxf(mx[j], __shfl_xor(mx[j], d));
        float alpha[4], rs[4];
        #pragma unroll
        for (int j = 0; j < 4; ++j) {
            float mn = fmaxf(m_run[j], mx[j]);
            alpha[j] = __expf(m_run[j] - mn);
            m_run[j] = mn;
            rs[j] = 0.f;
        }
        #pragma unroll
        for (int ct = 0; ct < 4; ++ct)
            #pragma unroll
            for (int j = 0; j < 4; ++j) {
                float e = __expf(p[ct][j] - m_run[j]);
                p[ct][j] = e;
                rs[j] += e;
            }
        #pragma unroll
        for (int d = 1; d < 16; d <<= 1)
            #pragma unroll
            for (int j = 0; j < 4; ++j) rs[j] += __shfl_xor(rs[j], d);
        #pragma unroll
        for (int j = 0; j < 4; ++j) l_run[j] = l_run[j] * alpha[j] + rs[j];
        #pragma unroll
        for (int dt = 0; dt < 4; ++dt)
            #pragma unroll
            for (int j = 0; j < 4; ++j) of[dt][j] *= alpha[j];
        // write P (wave-local region)
        #pragma unroll
        for (int ct = 0; ct < 4; ++ct)
            #pragma unroll
            for (int j = 0; j < 4; ++j)
                Ps[(w * 16 + qrow_lo + j) * 72 + ct * 16 + (lane & 15)] = (bf16)p[ct][j];
        asm volatile("s_waitcnt lgkmcnt(0)" ::: "memory");
        __builtin_amdgcn_sched_barrier(0);
        // O += P V
        bf16x8 ap0 = *reinterpret_cast<const bf16x8*>(Ps + (w * 16 + (lane & 15)) * 72 + (lane >> 4) * 8);
        bf16x8 ap1 = *reinterpret_cast<const bf16x8*>(Ps + (w * 16 + (lane & 15)) * 72 + 32 + (lane >> 4) * 8);
        #pragma unroll
        for (int dt = 0; dt < 4; ++dt) {
            bf16x8 bv0 = *reinterpret_cast<const bf16x8*>(Vt + (dt * 16 + (lane & 15)) * 72 + (lane >> 4) * 8);
            bf16x8 bv1 = *reinterpret_cast<const bf16x8*>(Vt + (dt * 16 + (lane & 15)) * 72 + 32 + (lane >> 4) * 8);
            of[dt] = MFMA_BF16(ap0, bv0, of[dt]);
            of[dt] = MFMA_BF16(ap1, bv1, of[dt]);
        }
        __syncthreads();
    }
    float inv[4];
    #pragma unroll
    for (int j = 0; j < 4; ++j) inv[j] = 1.f / l_run[j];
    #pragma unroll
    for (int dt = 0; dt < 4; ++dt)
        #pragma unroll
        for (int j = 0; j < 4; ++j)
            sab[((size_t)(b * N_ + r0 + w * 16 + qrow_lo + j)) * C_ + h * 64 + dt * 16 + (lane & 15)] =
                (bf16)(of[dt][j] * inv[j]);
}

// ============ MFMA flash cross-attention (sim/ds/gb biases) ============
__global__ __launch_bounds__(256) void attn_cross_m(
    const float* __restrict__ cq, const float* __restrict__ ck, const float* __restrict__ cv,
    const float* __restrict__ dn, const float* __restrict__ ds, const float* __restrict__ gb,
    const float* __restrict__ rdb, bf16* __restrict__ cob)
{
    __shared__ bf16 Kt[64 * 72];
    __shared__ bf16 Vt[64 * 72];
    __shared__ bf16 Ps[64 * 72];
    __shared__ float4 dnms[64];
    const int t = threadIdx.x, w = t >> 6, lane = t & 63;
    const int b = blockIdx.z, h = blockIdx.y, r0 = blockIdx.x * 64;
    const size_t rowbase = (size_t)b * N_;
    const float rdbh = rdb[h];

    for (int i = t; i < 1024; i += 256) {
        int row = i >> 4, c4 = (i & 15) * 4;
        float4 v = *reinterpret_cast<const float4*>(cq + (rowbase + r0 + row) * C_ + h * 64 + c4);
        *reinterpret_cast<bf16x4*>(Kt + row * 72 + c4) = (bf16x4){(bf16)v.x, (bf16)v.y, (bf16)v.z, (bf16)v.w};
    }
    __syncthreads();
    bf16x8 aq[2];
    aq[0] = *reinterpret_cast<const bf16x8*>(Kt + (w * 16 + (lane & 15)) * 72 + (lane >> 4) * 8);
    aq[1] = *reinterpret_cast<const bf16x8*>(Kt + (w * 16 + (lane & 15)) * 72 + 32 + (lane >> 4) * 8);
    __syncthreads();

    const int qrow_lo = (lane >> 4) * 4;
    float dqx[4], dqy[4], dqz[4], dsr[4];
    #pragma unroll
    for (int j = 0; j < 4; ++j) {
        const size_t rg = rowbase + r0 + w * 16 + qrow_lo + j;
        dqx[j] = dn[rg * 4 + 0];
        dqy[j] = dn[rg * 4 + 1];
        dqz[j] = dn[rg * 4 + 2];
        dsr[j] = 1.0f + ds[rg * NH_ + h];
    }

    float m_run[4], l_run[4];
    f32x4 of[4];
    #pragma unroll
    for (int j = 0; j < 4; ++j) { m_run[j] = -3e38f; l_run[j] = 0.f; }
    #pragma unroll
    for (int dt = 0; dt < 4; ++dt) of[dt] = (f32x4){0.f, 0.f, 0.f, 0.f};

    for (int mt = 0; mt < 16; ++mt) {
        for (int i = t; i < 1024; i += 256) {
            int row = i >> 4, c4 = (i & 15) * 4;
            float4 kv = *reinterpret_cast<const float4*>(ck + (rowbase + mt * 64 + row) * C_ + h * 64 + c4);
            *reinterpret_cast<bf16x4*>(Kt + row * 72 + c4) = (bf16x4){(bf16)kv.x, (bf16)kv.y, (bf16)kv.z, (bf16)kv.w};
            float4 vv = *reinterpret_cast<const float4*>(cv + (rowbase + mt * 64 + row) * C_ + h * 64 + c4);
            Vt[(c4 + 0) * 72 + row] = (bf16)vv.x;
            Vt[(c4 + 1) * 72 + row] = (bf16)vv.y;
            Vt[(c4 + 2) * 72 + row] = (bf16)vv.z;
            Vt[(c4 + 3) * 72 + row] = (bf16)vv.w;
        }
        if (t < 64) {
            float4 d4 = *reinterpret_cast<const float4*>(dn + (rowbase + mt * 64 + t) * 4);
            dnms[t] = make_float4(d4.x, d4.y, d4.z, gb[(rowbase + mt * 64 + t) * NH_ + h]);
        }
        __syncthreads();

        f32x4 sf[4];
        #pragma unroll
        for (int ct = 0; ct < 4; ++ct) {
            f32x4 a = (f32x4){0.f, 0.f, 0.f, 0.f};
            bf16x8 bk0 = *reinterpret_cast<const bf16x8*>(Kt + (ct * 16 + (lane & 15)) * 72 + (lane >> 4) * 8);
            bf16x8 bk1 = *reinterpret_cast<const bf16x8*>(Kt + (ct * 16 + (lane & 15)) * 72 + 32 + (lane >> 4) * 8);
            a = MFMA_BF16(aq[0], bk0, a);
            a = MFMA_BF16(aq[1], bk1, a);
            sf[ct] = a;
        }
        float p[4][4], mx[4];
        #pragma unroll
        for (int j = 0; j < 4; ++j) mx[j] = -3e38f;
        #pragma unroll
        for (int ct = 0; ct < 4; ++ct) {
            const float4 dm = dnms[ct * 16 + (lane & 15)];
            #pragma unroll
            for (int j = 0; j < 4; ++j) {
                float sim = dqx[j] * dm.x + dqy[j] * dm.y + dqz[j] * dm.z;
                float s = (sf[ct][j] * SCALE_ + sim * rdbh) * dsr[j] + dm.w;
                p[ct][j] = s;
                mx[j] = fmaxf(mx[j], s);
            }
        }
        #pragma unroll
        for (int d = 1; d < 16; d <<= 1)
            #pragma unroll
            for (int j = 0; j < 4; ++j) mx[j] = fmaxf(mx[j], __shfl_xor(mx[j], d));
        float alpha[4], rs[4];
        #pragma unroll
        for (int j = 0; j < 4; ++j) {
            float mn = fmaxf(m_run[j], mx[j]);
            alpha[j] = __expf(m_run[j] - mn);
            m_run[j] = mn;
            rs[j] = 0.f;
        }
        #pragma unroll
        for (int ct = 0; ct < 4; ++ct)
            #pragma unroll
            for (int j = 0; j < 4; ++j) {
                float e = __expf(p[ct][j] - m_run[j]);
                p[ct][j] = e;
                rs[j] += e;
            }
        #pragma unroll
        for (int d = 1; d < 16; d <<= 1)
            #pragma unroll
            for (int j = 0; j < 4; ++j) rs[j] += __shfl_xor(rs[j], d);
        #pragma unroll
        for (int j = 0; j < 4; ++j) l_run[j] = l_run[j] * alpha[j] + rs[j];
        #pragma unroll
        for (int dt = 0; dt < 4; ++dt)
            #pragma unroll
            for (int j = 0; j < 4; ++j) of[dt][j] *= alpha[j];
        #pragma unroll
        for (int ct = 0; ct < 4; ++ct)
            #pragma unroll
            for (int j = 0; j < 4; ++j)
                Ps[(w * 16 + qrow_lo + j) * 72 + ct * 16 + (lane & 15)] = (bf16)p[ct][j];
        asm volatile("s_waitcnt lgkmcnt(0)" ::: "memory");
        __builtin_amdgcn_sched_barrier(0);
        bf16x8 ap0 = *reinterpret_cast<const bf16x8*>(Ps + (w * 16 + (lane & 15)) * 72 + (lane >> 4) * 8);
        bf16x8 ap1 = *reinterpret_cast<const bf16x8*>(Ps + (w * 16 + (lane & 15)) * 72 + 32 + (lane >> 4) * 8);
        #pragma unroll
        for (int dt = 0; dt < 4; ++dt) {
            bf16x8 bv0 = *reinterpret_cast<const bf16x8*>(Vt + (dt * 16 + (lane & 15)) * 72 + (lane >> 4) * 8);
            bf16x8 bv1 = *reinterpret_cast<const bf16x8*>(Vt + (dt * 16 + (lane & 15)) * 72 + 32 + (lane >> 4) * 8);
            of[dt] = MFMA_BF16(ap0, bv0, of[dt]);
            of[dt] = MFMA_BF16(ap1, bv1, of[dt]);
        }
        __syncthreads();
    }
    float inv[4];
    #pragma unroll
    for (int j = 0; j < 4; ++j) inv[j] = 1.f / l_run[j];
    #pragma unroll
    for (int dt = 0; dt < 4; ++dt)
        #pragma unroll
        for (int j = 0; j < 4; ++j)
            cob[(rowbase + r0 + w * 16 + qrow_lo + j) * C_ + h * 64 + dt * 16 + (lane & 15)] =
                (bf16)(of[dt][j] * inv[j]);
}

// ============ plucker MLP (pp), ds MLP, dn normalize ============
__global__ __launch_bounds__(256) void plucker_k(
    const float* __restrict__ pl,
    const float* __restrict__ w1, const float* __restrict__ b1,
    const float* __restrict__ w2, const float* __restrict__ b2,
    const float* __restrict__ w3, const float* __restrict__ b3,
    const float* __restrict__ dw1, const float* __restrict__ db1,
    const float* __restrict__ dw2, const float* __restrict__ db2,
    float* __restrict__ pp, float* __restrict__ ds, float* __restrict__ dn)
{
    const int row = blockIdx.x;
    const int t = threadIdx.x;
    __shared__ float plr[6];
    __shared__ float h1[256];
    __shared__ float h2[128];
    __shared__ float dh[64];
    if (t < 6) plr[t] = pl[(size_t)row * 6 + t];
    __syncthreads();
    {
        float a = b1[t];
        #pragma unroll
        for (int j = 0; j < 6; ++j) a = fmaf(plr[j], w1[j * 256 + t], a);
        h1[t] = gelu_f(a);
    }
    if (t < 64) {
        float d = db1[t];
        #pragma unroll
        for (int j = 0; j < 6; ++j) d = fmaf(plr[j], dw1[j * 64 + t], d);
        dh[t] = gelu_f(d);
    }
    if (t == 0) {
        float x = plr[0], y = plr[1], z = plr[2];
        float nrm = fmaxf(sqrtf(x * x + y * y + z * z), 1e-12f);
        dn[(size_t)row * 4 + 0] = x / nrm;
        dn[(size_t)row * 4 + 1] = y / nrm;
        dn[(size_t)row * 4 + 2] = z / nrm;
        dn[(size_t)row * 4 + 3] = 0.f;
    }
    __syncthreads();
    if (t < 128) {
        float a = b2[t];
        for (int j = 0; j < 256; ++j) a = fmaf(h1[j], w2[j * 128 + t], a);
        h2[t] = gelu_f(a);
    }
    if (t < 16) {
        float d = db2[t];
        for (int j = 0; j < 64; ++j) d = fmaf(dh[j], dw2[j * 16 + t], d);
        ds[(size_t)row * 16 + t] = tanhf(d);
    }
    __syncthreads();
    if (t < 128) {
        float a = b3[t];
        for (int j = 0; j < 128; ++j) a = fmaf(h2[j], w3[j * 128 + t], a);
        pp[(size_t)row * 128 + t] = a;
    }
}

// ============ spatial diffs ============
__global__ __launch_bounds__(256) void sd_k(const float* __restrict__ pp, float* __restrict__ sd)
{
    int g = blockIdx.x * 256 + threadIdx.x;
    if (g >= B_ * N_ * PP_) return;
    const int c = g & 127;
    const int rown = g >> 7;
    const int n = rown & (N_ - 1);
    const int xx = n & 31, yy = (n >> 5) & 31;
    const float cur = pp[g];
    const float hd = (xx < 31) ? fabsf(pp[g + PP_] - cur) : 0.f;
    const float vd = (yy < 31) ? fabsf(pp[g + 32 * PP_] - cur) : 0.f;
    sd[(size_t)rown * 256 + c] = hd;
    sd[(size_t)rown * 256 + 128 + c] = vd;
}

// ============ gb MLP ============
__global__ __launch_bounds__(256) void gb_k(
    const float* __restrict__ sd,
    const float* __restrict__ w1, const float* __restrict__ b1,
    const float* __restrict__ w2, const float* __restrict__ b2,
    float* __restrict__ gbv)
{
    const int row = blockIdx.x;
    const int t = threadIdx.x;
    __shared__ float s[256];
    __shared__ float h[512];
    s[t] = sd[(size_t)row * 256 + t];
    __syncthreads();
    #pragma unroll
    for (int o = 0; o < 2; ++o) {
        const int c = t + o * 256;
        float a = b1[c];
        for (int j = 0; j < 256; ++j) a = fmaf(s[j], w1[j * 512 + c], a);
        h[c] = gelu_f(a);
    }
    __syncthreads();
    if (t < 16) {
        float a = b2[t];
        for (int j = 0; j < 512; ++j) a = fmaf(h[j], w2[j * 16 + t], a);
        gbv[(size_t)row * 16 + t] = tanhf(a);
    }
}

// ============ concat [co_p(bf16) | pp(fp32->bf16)] ============
__global__ __launch_bounds__(256) void cat_k(
    const bf16* __restrict__ cop, const float* __restrict__ pp, bf16* __restrict__ cat)
{
    int g = blockIdx.x * 256 + threadIdx.x;
    if (g >= B_ * N_ * 1152 / 4) return;
    const int r = g / 288, c4 = (g % 288) * 4;
    bf16x4 o;
    if (c4 < 1024) {
        o = *reinterpret_cast<const bf16x4*>(cop + (size_t)r * 1024 + c4);
    } else {
        float4 v = *reinterpret_cast<const float4*>(pp + (size_t)r * 128 + (c4 - 1024));
        o = (bf16x4){(bf16)v.x, (bf16)v.y, (bf16)v.z, (bf16)v.w};
    }
    *reinterpret_cast<bf16x4*>(cat + (size_t)r * 1152 + c4) = o;
}

extern "C" void kernel_launch(void* const* d_in, const int* in_sizes, int n_in,
                              void* d_out, int out_size, void* d_ws, size_t ws_size,
                              hipStream_t stream)
{
    const float* x     = (const float*)d_in[0];
    const float* pl    = (const float*)d_in[1];
    const float* w_qkv = (const float*)d_in[2];
    const float* w_sp  = (const float*)d_in[3];
    const float* b_sp  = (const float*)d_in[4];
    const float* pl_w1 = (const float*)d_in[5];
    const float* pl_b1 = (const float*)d_in[6];
    const float* pl_w2 = (const float*)d_in[7];
    const float* pl_b2 = (const float*)d_in[8];
    const float* pl_w3 = (const float*)d_in[9];
    const float* pl_b3 = (const float*)d_in[10];
    const float* w_cq  = (const float*)d_in[11];
    const float* w_pk  = (const float*)d_in[12];
    const float* w_pv  = (const float*)d_in[13];
    const float* w_cp  = (const float*)d_in[14];
    const float* b_cp  = (const float*)d_in[15];
    const float* rdb   = (const float*)d_in[16];
    const float* ds_w1 = (const float*)d_in[17];
    const float* ds_b1 = (const float*)d_in[18];
    const float* ds_w2 = (const float*)d_in[19];
    const float* ds_b2 = (const float*)d_in[20];
    const float* gb_w1 = (const float*)d_in[21];
    const float* gb_b1 = (const float*)d_in[22];
    const float* gb_w2 = (const float*)d_in[23];
    const float* gb_b2 = (const float*)d_in[24];
    const float* rel_t = (const float*)d_in[25];
    const float* gfw1  = (const float*)d_in[26];
    const float* gfb1  = (const float*)d_in[27];
    const float* gfw2  = (const float*)d_in[28];
    const float* gfb2  = (const float*)d_in[29];

    char* W = (char*)d_ws;
    float* out = (float*)d_out;
    const size_t MB = 1ull << 20;

    float* qkv   = (float*)(W + 0);          // 48MB; after self-attn reused:
    float* cqb   = (float*)(W + 0);          //   16MB
    float* ckb   = (float*)(W + 16 * MB);    //   16MB
    float* cvb   = (float*)(W + 32 * MB);    //   16MB
    bf16* xb     = (bf16*)(W + 48 * MB);     // 8MB
    bf16* wqkvT  = (bf16*)(W + 56 * MB);     // 6MB
    bf16* wspT   = (bf16*)(W + 62 * MB);     // 2MB
    bf16* wcqT   = (bf16*)(W + 64 * MB);     // 2MB
    bf16* wpkT   = (bf16*)(W + 66 * MB);     // 0.25MB
    bf16* wpvT   = (bf16*)(W + 66 * MB + 262144); // 0.25MB
    bf16* wcpT   = (bf16*)(W + 67 * MB);     // 2MB
    bf16* gfw1T  = (bf16*)(W + 69 * MB);     // 2.25MB
    bf16* gfw2T  = (bf16*)(W + 72 * MB);     // 2MB
    bf16* sab    = (bf16*)(W + 74 * MB);     // 8MB ; cob reuses
    bf16* cob    = sab;
    bf16* sapb   = (bf16*)(W + 82 * MB);     // 8MB ; copb reuses
    bf16* copb   = sapb;
    float* pp    = (float*)(W + 90 * MB);    // 2MB
    bf16* ppb    = (bf16*)(W + 92 * MB);     // 1MB
    float* sdb   = (float*)(W + 93 * MB);    // 4MB
    float* dsb   = (float*)(W + 97 * MB);    // 256KB
    float* dnb   = (float*)(W + 97 * MB + 262144);  // 64KB
    float* gbb   = (float*)(W + 97 * MB + 327680);  // 256KB
    bf16* catb   = (bf16*)(W + 98 * MB);     // 9MB
    bf16* hidb   = (bf16*)(W + 107 * MB);    // 8MB  -> total 115MB

    const dim3 blk(256);

    // 1. transpose-cast all weights to bf16 [N,K]
    TJobs J;
    J.src[0] = w_qkv; J.dst[0] = wqkvT; J.K[0] = 1024; J.N[0] = 3072;
    J.src[1] = w_sp;  J.dst[1] = wspT;  J.K[1] = 1024; J.N[1] = 1024;
    J.src[2] = w_cq;  J.dst[2] = wcqT;  J.K[2] = 1024; J.N[2] = 1024;
    J.src[3] = w_pk;  J.dst[3] = wpkT;  J.K[3] = 128;  J.N[3] = 1024;
    J.src[4] = w_pv;  J.dst[4] = wpvT;  J.K[4] = 128;  J.N[4] = 1024;
    J.src[5] = w_cp;  J.dst[5] = wcpT;  J.K[5] = 1024; J.N[5] = 1024;
    J.src[6] = gfw1;  J.dst[6] = gfw1T; J.K[6] = 1152; J.N[6] = 1024;
    J.src[7] = gfw2;  J.dst[7] = gfw2T; J.K[7] = 1024; J.N[7] = 1024;
    tcast_k<<<dim3(96, 36, 8), blk, 0, stream>>>(J);
    // 2. cast x
    cast_rm<<<4096, blk, 0, stream>>>(x, xb, 1048576);
    // 3. qkv GEMM (fp32 out)
    gemm_m<<<dim3(48, 32), blk, 0, stream>>>(xb, wqkvT, nullptr, nullptr, qkv, nullptr, 4096, 3072, 1024, 0);
    // 4. rope q,k in place
    rope_pair<<<dim3(8192, 2), blk, 0, stream>>>(qkv, qkv, 3072, 0, 1024);
    // 5. self attention
    attn_self_m<<<dim3(16, 16, 4), blk, 0, stream>>>(qkv, rel_t, sab);
    // 6. self proj -> bf16
    gemm_m<<<dim3(16, 32), blk, 0, stream>>>(sab, wspT, b_sp, nullptr, nullptr, sapb, 4096, 1024, 1024, 0);
    // 7. plucker MLPs
    plucker_k<<<4096, blk, 0, stream>>>(pl, pl_w1, pl_b1, pl_w2, pl_b2, pl_w3, pl_b3,
                                        ds_w1, ds_b1, ds_w2, ds_b2, pp, dsb, dnb);
    // 8. cast pp
    cast_rm<<<512, blk, 0, stream>>>(pp, ppb, 131072);
    // 9-11. cq / ck / cv (fp32 out for rope/attn staging)
    gemm_m<<<dim3(16, 32), blk, 0, stream>>>(sapb, wcqT, nullptr, nullptr, cqb, nullptr, 4096, 1024, 1024, 0);
    gemm_m<<<dim3(16, 32), blk, 0, stream>>>(ppb, wpkT, nullptr, nullptr, ckb, nullptr, 4096, 1024, 128, 0);
    gemm_m<<<dim3(16, 32), blk, 0, stream>>>(ppb, wpvT, nullptr, nullptr, cvb, nullptr, 4096, 1024, 128, 0);
    // 12. rope cq, ck
    rope_pair<<<dim3(8192, 2), blk, 0, stream>>>(cqb, ckb, 1024, 0, 0);
    // 13-14. spatial diffs + gb MLP
    sd_k<<<2048, blk, 0, stream>>>(pp, sdb);
    gb_k<<<4096, blk, 0, stream>>>(sdb, gb_w1, gb_b1, gb_w2, gb_b2, gbb);
    // 15. cross attention
    attn_cross_m<<<dim3(16, 16, 4), blk, 0, stream>>>(cqb, ckb, cvb, dnb, dsb, gbb, rdb, cob);
    // 16. cross proj -> bf16
    gemm_m<<<dim3(16, 32), blk, 0, stream>>>(cob, wcpT, b_cp, nullptr, nullptr, copb, 4096, 1024, 1024, 0);
    // 17. concat
    cat_k<<<4608, blk, 0, stream>>>(copb, pp, catb);
    // 18. gfe1 (gelu) -> bf16
    gemm_m<<<dim3(16, 32), blk, 0, stream>>>(catb, gfw1T, gfb1, nullptr, nullptr, hidb, 4096, 1024, 1152, 1);
    // 19. gfe2 + bias + residual -> fp32 out
    gemm_m<<<dim3(16, 32), blk, 0, stream>>>(hidb, gfw2T, gfb2, x, out, nullptr, 4096, 1024, 1024, 0);
}

// Round 3
// 568.990 us; speedup vs baseline: 6.1904x; 1.1709x over previous
//
#include <hip/hip_runtime.h>
#include <math.h>

#define B_ 4
#define N_ 1024
#define C_ 1024
#define NH_ 16
#define HD_ 64
#define PP_ 128

typedef __bf16 bf16;
typedef __attribute__((ext_vector_type(8))) __bf16 bf16x8;
typedef __attribute__((ext_vector_type(4))) __bf16 bf16x4;
typedef __attribute__((ext_vector_type(4))) float f32x4;

#define MFMA_BF16(a, b, c) __builtin_amdgcn_mfma_f32_16x16x32_bf16((a), (b), (c), 0, 0, 0)

__device__ __forceinline__ float gelu_f(float x) {
    return 0.5f * x * (1.0f + erff(x * 0.70710678118654752f));
}

__device__ __forceinline__ void gload16(const void* g, void* l) {
    __builtin_amdgcn_global_load_lds(
        (const __attribute__((address_space(1))) void*)g,
        (__attribute__((address_space(3))) void*)l, 16, 0, 0);
}

// stage a 64-row x 128B tile into LDS with XOR-swizzle (source pre-swizzled,
// LDS dest linear for global_load_lds). 256 threads, 2 chunks each.
__device__ __forceinline__ void stage64_swz(const bf16* __restrict__ g, int pitchB,
                                            bf16* lds, int t) {
    #pragma unroll
    for (int r = 0; r < 2; ++r) {
        int i = r * 256 + t;
        int row = i >> 3, c = i & 7;
        const char* src = (const char*)g + (size_t)row * pitchB + ((c ^ (row & 7)) << 4);
        bf16* dst = lds + (size_t)(r * 256 + (t & 192)) * 8;   // wave-uniform base
        gload16(src, dst);
    }
}

__device__ __forceinline__ bf16x8 lds8_swz(const bf16* lds, int row, int colb) {
    return *reinterpret_cast<const bf16x8*>(
        (const char*)lds + row * 128 + (colb ^ ((row & 7) << 4)));
}

// ============ rope table: rt[n*32+i] = (cos, sin) of n * 10000^(-2i/64) ============
__global__ __launch_bounds__(256) void rope_tab_k(float2* __restrict__ rt)
{
    int g = blockIdx.x * 256 + threadIdx.x;   // 32768
    const int n = g >> 5, i = g & 31;
    const float inv = powf(10000.0f, -(float)(2 * i) / 64.0f);
    const float ang = (float)n * inv;
    rt[g] = make_float2(cosf(ang), sinf(ang));
}

// ============ transpose-cast fp32 W[K,N] -> bf16 Wt[N,K] (8 jobs) ============
struct TJobs {
    const float* src[8];
    bf16* dst[8];
    int K[8];
    int N[8];
};

__global__ __launch_bounds__(256) void tcast_k(TJobs J)
{
    const int j = blockIdx.z;
    const int Kd = J.K[j], Nd = J.N[j];
    const int n0 = blockIdx.x * 32, k0 = blockIdx.y * 32;
    if (n0 >= Nd || k0 >= Kd) return;
    __shared__ float tl[32][33];
    const int t = threadIdx.x, tx = t & 31, ty = t >> 5;
    const float* src = J.src[j];
    bf16* dst = J.dst[j];
    #pragma unroll
    for (int r = 0; r < 4; ++r) {
        int kk = ty + r * 8;
        tl[kk][tx] = src[(size_t)(k0 + kk) * Nd + n0 + tx];
    }
    __syncthreads();
    #pragma unroll
    for (int r = 0; r < 4; ++r) {
        int nn = ty + r * 8;
        dst[(size_t)(n0 + nn) * Kd + k0 + tx] = (bf16)tl[tx][nn];
    }
}

// ============ elementwise cast fp32 -> bf16 ============
__global__ __launch_bounds__(256) void cast_rm(const float* __restrict__ in,
                                               bf16* __restrict__ out, int n4)
{
    int g = blockIdx.x * 256 + threadIdx.x;
    if (g >= n4) return;
    float4 v = reinterpret_cast<const float4*>(in)[g];
    bf16x4 o = {(bf16)v.x, (bf16)v.y, (bf16)v.z, (bf16)v.w};
    reinterpret_cast<bf16x4*>(out)[g] = o;
}

// ============ MFMA GEMM with fused epilogues ============
// C[M,N] = A[M,K] @ Bt[N,K]^T. tile 128x64, BK=32, 4 waves.
// epi: 0=fp32 rowmajor(+bias,+gelu,+resid) 1=bf16 rowmajor(+bias,+gelu)
//      2=qkv split (rope q,k; q*=scale; v transposed)  [out0=q out1=k out2=vt]
//      3=head-major bf16 + rope, *=scale               [out0]
//      4=head-major transposed bf16                    [out0]
__global__ __launch_bounds__(256) void gemm_m(
    const bf16* __restrict__ A, const bf16* __restrict__ Bt,
    const float* __restrict__ bias, const float* __restrict__ resid,
    void* __restrict__ out0, void* __restrict__ out1, void* __restrict__ out2,
    const float2* __restrict__ rtab,
    int M, int N, int K, int epi, int act_gelu, float scale)
{
    __shared__ bf16 As[128 * 32];
    __shared__ bf16 Bs[64 * 32];
    const int t = threadIdx.x;
    const int w = t >> 6, lane = t & 63;
    const int row0 = blockIdx.y * 128, col0 = blockIdx.x * 64;
    const int wm = w >> 1, wn = w & 1;
    f32x4 acc[4][2];
    #pragma unroll
    for (int mi = 0; mi < 4; ++mi)
        #pragma unroll
        for (int ni = 0; ni < 2; ++ni)
            acc[mi][ni] = (f32x4){0.f, 0.f, 0.f, 0.f};

    for (int k0 = 0; k0 < K; k0 += 32) {
        #pragma unroll
        for (int r = 0; r < 2; ++r) {
            int c = r * 256 + t;
            const bf16* src = A + (size_t)(row0 + (c >> 2)) * K + k0 + (c & 3) * 8;
            bf16* dst = As + (size_t)(r * 256 + w * 64) * 8;
            gload16(src, dst);
        }
        {
            const bf16* src = Bt + (size_t)(col0 + (t >> 2)) * K + k0 + (t & 3) * 8;
            bf16* dst = Bs + (size_t)(w * 64) * 8;
            gload16(src, dst);
        }
        __syncthreads();
        bf16x8 af[4], bfv[2];
        #pragma unroll
        for (int mi = 0; mi < 4; ++mi)
            af[mi] = *reinterpret_cast<const bf16x8*>(
                As + (wm * 64 + mi * 16 + (lane & 15)) * 32 + (lane >> 4) * 8);
        #pragma unroll
        for (int ni = 0; ni < 2; ++ni)
            bfv[ni] = *reinterpret_cast<const bf16x8*>(
                Bs + (wn * 32 + ni * 16 + (lane & 15)) * 32 + (lane >> 4) * 8);
        #pragma unroll
        for (int mi = 0; mi < 4; ++mi)
            #pragma unroll
            for (int ni = 0; ni < 2; ++ni)
                acc[mi][ni] = MFMA_BF16(af[mi], bfv[ni], acc[mi][ni]);
        __syncthreads();
    }

    #pragma unroll
    for (int mi = 0; mi < 4; ++mi) {
        #pragma unroll
        for (int ni = 0; ni < 2; ++ni) {
            const int col = col0 + wn * 32 + ni * 16 + (lane & 15);
            if (epi <= 1) {
                const float bv = bias ? bias[col] : 0.f;
                #pragma unroll
                for (int j = 0; j < 4; ++j) {
                    const int row = row0 + wm * 64 + mi * 16 + (lane >> 4) * 4 + j;
                    float v = acc[mi][ni][j] + bv;
                    if (act_gelu) v = gelu_f(v);
                    if (epi == 0) {
                        if (resid) v += resid[(size_t)row * N + col];
                        ((float*)out0)[(size_t)row * N + col] = v;
                    } else {
                        ((bf16*)out0)[(size_t)row * N + col] = (bf16)v;
                    }
                }
            } else if (epi == 2) {
                const int reg = col >> 10;         // 0=q 1=k 2=v
                const int h = (col >> 6) & 15, d = col & 63;
                if (reg <= 1) {
                    bf16* dst = reg == 0 ? (bf16*)out0 : (bf16*)out1;
                    const float sc = reg == 0 ? scale : 1.0f;
                    #pragma unroll
                    for (int j = 0; j < 4; ++j) {
                        const int row = row0 + wm * 64 + mi * 16 + (lane >> 4) * 4 + j;
                        const int b = row >> 10, n = row & 1023;
                        float v = acc[mi][ni][j];
                        float pv = __shfl_xor(v, 1);
                        float2 cs = rtab[(n << 5) + (d >> 1)];
                        float o = (d & 1) == 0 ? v * cs.x - pv * cs.y
                                               : v * cs.x + pv * cs.y;
                        dst[((size_t)((b * 16 + h) * 1024 + n)) * 64 + d] = (bf16)(o * sc);
                    }
                } else {
                    bf16x4 o4;
                    #pragma unroll
                    for (int j = 0; j < 4; ++j) o4[j] = (bf16)acc[mi][ni][j];
                    const int row = row0 + wm * 64 + mi * 16 + (lane >> 4) * 4;
                    const int b = row >> 10, n = row & 1023;
                    *reinterpret_cast<bf16x4*>(
                        (bf16*)out2 + ((size_t)((b * 16 + h) * 64 + d)) * 1024 + n) = o4;
                }
            } else if (epi == 3) {
                const int h = (col >> 6) & 15, d = col & 63;
                #pragma unroll
                for (int j = 0; j < 4; ++j) {
                    const int row = row0 + wm * 64 + mi * 16 + (lane >> 4) * 4 + j;
                    const int b = row >> 10, n = row & 1023;
                    float v = acc[mi][ni][j];
                    float pv = __shfl_xor(v, 1);
                    float2 cs = rtab[(n << 5) + (d >> 1)];
                    float o = (d & 1) == 0 ? v * cs.x - pv * cs.y
                                           : v * cs.x + pv * cs.y;
                    ((bf16*)out0)[((size_t)((b * 16 + h) * 1024 + n)) * 64 + d] = (bf16)(o * scale);
                }
            } else {  // epi == 4: transposed head-major
                const int h = (col >> 6) & 15, d = col & 63;
                bf16x4 o4;
                #pragma unroll
                for (int j = 0; j < 4; ++j) o4[j] = (bf16)acc[mi][ni][j];
                const int row = row0 + wm * 64 + mi * 16 + (lane >> 4) * 4;
                const int b = row >> 10, n = row & 1023;
                *reinterpret_cast<bf16x4*>(
                    (bf16*)out0 + ((size_t)((b * 16 + h) * 64 + d)) * 1024 + n) = o4;
            }
        }
    }
}

// ============ XCD-aware block decomposition for attention ============
// 1024 blocks; all 16 q-tiles of one (b,h) land on one XCD.
__device__ __forceinline__ void attn_bid(int bid, int& bh, int& r0t) {
    const int xcd = bid & 7, s = bid >> 3;
    bh = (s >> 4) * 8 + xcd;   // 0..63
    r0t = s & 15;
}

// ============ MFMA flash self-attention (bf16 head-major inputs) ============
__global__ __launch_bounds__(256) void attn_self_m(
    const bf16* __restrict__ qb, const bf16* __restrict__ kb, const bf16* __restrict__ vtb,
    const float* __restrict__ rel_table, bf16* __restrict__ sab)
{
    __shared__ bf16 Ks[64 * 64];
    __shared__ bf16 Vs[64 * 64];
    __shared__ bf16 Ps[64 * 72];
    const int t = threadIdx.x, w = t >> 6, lane = t & 63;
    int bh, r0t;
    attn_bid(blockIdx.x, bh, r0t);
    const int b = bh >> 4, h = bh & 15, r0 = r0t * 64;

    // stage Q (into Ks temp), pull A-frags
    stage64_swz(qb + ((size_t)bh * 1024 + r0) * 64, 128, Ks, t);
    __syncthreads();
    bf16x8 aq[2];
    {
        const int qr = w * 16 + (lane & 15);
        aq[0] = lds8_swz(Ks, qr, (lane >> 4) * 16);
        aq[1] = lds8_swz(Ks, qr, 64 + (lane >> 4) * 16);
    }
    __syncthreads();

    float m_run[4], l_run[4];
    f32x4 of[4];
    #pragma unroll
    for (int j = 0; j < 4; ++j) { m_run[j] = -3e38f; l_run[j] = 0.f; }
    #pragma unroll
    for (int dt = 0; dt < 4; ++dt) of[dt] = (f32x4){0.f, 0.f, 0.f, 0.f};

    const int qrow_lo = (lane >> 4) * 4;
    int yn[4], xn[4];
    #pragma unroll
    for (int j = 0; j < 4; ++j) {
        int qg = r0 + w * 16 + qrow_lo + j;
        yn[j] = qg >> 5; xn[j] = qg & 31;
    }

    for (int mt = 0; mt < 16; ++mt) {
        stage64_swz(kb + ((size_t)bh * 1024 + mt * 64) * 64, 128, Ks, t);
        stage64_swz(vtb + (size_t)bh * 65536 + (size_t)mt * 64, 2048, Vs, t);
        __syncthreads();

        f32x4 sf[4];
        #pragma unroll
        for (int ct = 0; ct < 4; ++ct) {
            const int kr = ct * 16 + (lane & 15);
            f32x4 a = (f32x4){0.f, 0.f, 0.f, 0.f};
            a = MFMA_BF16(aq[0], lds8_swz(Ks, kr, (lane >> 4) * 16), a);
            a = MFMA_BF16(aq[1], lds8_swz(Ks, kr, 64 + (lane >> 4) * 16), a);
            sf[ct] = a;
        }
        float p[4][4], mx[4];
        #pragma unroll
        for (int j = 0; j < 4; ++j) mx[j] = -3e38f;
        #pragma unroll
        for (int ct = 0; ct < 4; ++ct) {
            const int mg = mt * 64 + ct * 16 + (lane & 15);
            const int ym = mg >> 5, xm = mg & 31;
            #pragma unroll
            for (int j = 0; j < 4; ++j) {
                float s = sf[ct][j] + rel_table[(size_t)((yn[j] - ym + 31) * 63 + (xn[j] - xm + 31)) * NH_ + h];
                p[ct][j] = s;
                mx[j] = fmaxf(mx[j], s);
            }
        }
        #pragma unroll
        for (int d = 1; d < 16; d <<= 1)
            #pragma unroll
            for (int j = 0; j < 4; ++j) mx[j] = fmaxf(mx[j], __shfl_xor(mx[j], d));
        float alpha[4], rs[4];
        #pragma unroll
        for (int j = 0; j < 4; ++j) {
            float mn = fmaxf(m_run[j], mx[j]);
            alpha[j] = __expf(m_run[j] - mn);
            m_run[j] = mn;
            rs[j] = 0.f;
        }
        #pragma unroll
        for (int ct = 0; ct < 4; ++ct)
            #pragma unroll
            for (int j = 0; j < 4; ++j) {
                float e = __expf(p[ct][j] - m_run[j]);
                p[ct][j] = e;
                rs[j] += e;
            }
        #pragma unroll
        for (int d = 1; d < 16; d <<= 1)
            #pragma unroll
            for (int j = 0; j < 4; ++j) rs[j] += __shfl_xor(rs[j], d);
        #pragma unroll
        for (int j = 0; j < 4; ++j) l_run[j] = l_run[j] * alpha[j] + rs[j];
        #pragma unroll
        for (int dt = 0; dt < 4; ++dt)
            #pragma unroll
            for (int j = 0; j < 4; ++j) of[dt][j] *= alpha[j];
        #pragma unroll
        for (int ct = 0; ct < 4; ++ct)
            #pragma unroll
            for (int j = 0; j < 4; ++j)
                Ps[(w * 16 + qrow_lo + j) * 72 + ct * 16 + (lane & 15)] = (bf16)p[ct][j];
        asm volatile("s_waitcnt lgkmcnt(0)" ::: "memory");
        __builtin_amdgcn_sched_barrier(0);
        bf16x8 ap0 = *reinterpret_cast<const bf16x8*>(Ps + (w * 16 + (lane & 15)) * 72 + (lane >> 4) * 8);
        bf16x8 ap1 = *reinterpret_cast<const bf16x8*>(Ps + (w * 16 + (lane & 15)) * 72 + 32 + (lane >> 4) * 8);
        #pragma unroll
        for (int dt = 0; dt < 4; ++dt) {
            const int vr = dt * 16 + (lane & 15);
            of[dt] = MFMA_BF16(ap0, lds8_swz(Vs, vr, (lane >> 4) * 16), of[dt]);
            of[dt] = MFMA_BF16(ap1, lds8_swz(Vs, vr, 64 + (lane >> 4) * 16), of[dt]);
        }
        __syncthreads();
    }
    float inv[4];
    #pragma unroll
    for (int j = 0; j < 4; ++j) inv[j] = 1.f / l_run[j];
    #pragma unroll
    for (int dt = 0; dt < 4; ++dt)
        #pragma unroll
        for (int j = 0; j < 4; ++j)
            sab[((size_t)(b * N_ + r0 + w * 16 + qrow_lo + j)) * C_ + h * 64 + dt * 16 + (lane & 15)] =
                (bf16)(of[dt][j] * inv[j]);
}

// ============ MFMA flash cross-attention ============
__global__ __launch_bounds__(256) void attn_cross_m(
    const bf16* __restrict__ cq, const bf16* __restrict__ ck, const bf16* __restrict__ cvt,
    const float* __restrict__ dn, const float* __restrict__ ds, const float* __restrict__ gb,
    const float* __restrict__ rdb, bf16* __restrict__ cob)
{
    __shared__ bf16 Ks[64 * 64];
    __shared__ bf16 Vs[64 * 64];
    __shared__ bf16 Ps[64 * 72];
    __shared__ float4 dnms[64];
    const int t = threadIdx.x, w = t >> 6, lane = t & 63;
    int bh, r0t;
    attn_bid(blockIdx.x, bh, r0t);
    const int b = bh >> 4, h = bh & 15, r0 = r0t * 64;
    const size_t rowbase = (size_t)b * N_;
    const float rdbh = rdb[h];

    stage64_swz(cq + ((size_t)bh * 1024 + r0) * 64, 128, Ks, t);
    __syncthreads();
    bf16x8 aq[2];
    {
        const int qr = w * 16 + (lane & 15);
        aq[0] = lds8_swz(Ks, qr, (lane >> 4) * 16);
        aq[1] = lds8_swz(Ks, qr, 64 + (lane >> 4) * 16);
    }
    __syncthreads();

    const int qrow_lo = (lane >> 4) * 4;
    float dqx[4], dqy[4], dqz[4], dsr[4];
    #pragma unroll
    for (int j = 0; j < 4; ++j) {
        const size_t rg = rowbase + r0 + w * 16 + qrow_lo + j;
        dqx[j] = dn[rg * 4 + 0];
        dqy[j] = dn[rg * 4 + 1];
        dqz[j] = dn[rg * 4 + 2];
        dsr[j] = 1.0f + ds[rg * NH_ + h];
    }

    float m_run[4], l_run[4];
    f32x4 of[4];
    #pragma unroll
    for (int j = 0; j < 4; ++j) { m_run[j] = -3e38f; l_run[j] = 0.f; }
    #pragma unroll
    for (int dt = 0; dt < 4; ++dt) of[dt] = (f32x4){0.f, 0.f, 0.f, 0.f};

    for (int mt = 0; mt < 16; ++mt) {
        stage64_swz(ck + ((size_t)bh * 1024 + mt * 64) * 64, 128, Ks, t);
        stage64_swz(cvt + (size_t)bh * 65536 + (size_t)mt * 64, 2048, Vs, t);
        if (t < 64) {
            float4 d4 = *reinterpret_cast<const float4*>(dn + (rowbase + mt * 64 + t) * 4);
            dnms[t] = make_float4(d4.x, d4.y, d4.z, gb[(rowbase + mt * 64 + t) * NH_ + h]);
        }
        __syncthreads();

        f32x4 sf[4];
        #pragma unroll
        for (int ct = 0; ct < 4; ++ct) {
            const int kr = ct * 16 + (lane & 15);
            f32x4 a = (f32x4){0.f, 0.f, 0.f, 0.f};
            a = MFMA_BF16(aq[0], lds8_swz(Ks, kr, (lane >> 4) * 16), a);
            a = MFMA_BF16(aq[1], lds8_swz(Ks, kr, 64 + (lane >> 4) * 16), a);
            sf[ct] = a;
        }
        float p[4][4], mx[4];
        #pragma unroll
        for (int j = 0; j < 4; ++j) mx[j] = -3e38f;
        #pragma unroll
        for (int ct = 0; ct < 4; ++ct) {
            const float4 dm = dnms[ct * 16 + (lane & 15)];
            #pragma unroll
            for (int j = 0; j < 4; ++j) {
                float sim = dqx[j] * dm.x + dqy[j] * dm.y + dqz[j] * dm.z;
                float s = (sf[ct][j] + sim * rdbh) * dsr[j] + dm.w;
                p[ct][j] = s;
                mx[j] = fmaxf(mx[j], s);
            }
        }
        #pragma unroll
        for (int d = 1; d < 16; d <<= 1)
            #pragma unroll
            for (int j = 0; j < 4; ++j) mx[j] = fmaxf(mx[j], __shfl_xor(mx[j], d));
        float alpha[4], rs[4];
        #pragma unroll
        for (int j = 0; j < 4; ++j) {
            float mn = fmaxf(m_run[j], mx[j]);
            alpha[j] = __expf(m_run[j] - mn);
            m_run[j] = mn;
            rs[j] = 0.f;
        }
        #pragma unroll
        for (int ct = 0; ct < 4; ++ct)
            #pragma unroll
            for (int j = 0; j < 4; ++j) {
                float e = __expf(p[ct][j] - m_run[j]);
                p[ct][j] = e;
                rs[j] += e;
            }
        #pragma unroll
        for (int d = 1; d < 16; d <<= 1)
            #pragma unroll
            for (int j = 0; j < 4; ++j) rs[j] += __shfl_xor(rs[j], d);
        #pragma unroll
        for (int j = 0; j < 4; ++j) l_run[j] = l_run[j] * alpha[j] + rs[j];
        #pragma unroll
        for (int dt = 0; dt < 4; ++dt)
            #pragma unroll
            for (int j = 0; j < 4; ++j) of[dt][j] *= alpha[j];
        #pragma unroll
        for (int ct = 0; ct < 4; ++ct)
            #pragma unroll
            for (int j = 0; j < 4; ++j)
                Ps[(w * 16 + qrow_lo + j) * 72 + ct * 16 + (lane & 15)] = (bf16)p[ct][j];
        asm volatile("s_waitcnt lgkmcnt(0)" ::: "memory");
        __builtin_amdgcn_sched_barrier(0);
        bf16x8 ap0 = *reinterpret_cast<const bf16x8*>(Ps + (w * 16 + (lane & 15)) * 72 + (lane >> 4) * 8);
        bf16x8 ap1 = *reinterpret_cast<const bf16x8*>(Ps + (w * 16 + (lane & 15)) * 72 + 32 + (lane >> 4) * 8);
        #pragma unroll
        for (int dt = 0; dt < 4; ++dt) {
            const int vr = dt * 16 + (lane & 15);
            of[dt] = MFMA_BF16(ap0, lds8_swz(Vs, vr, (lane >> 4) * 16), of[dt]);
            of[dt] = MFMA_BF16(ap1, lds8_swz(Vs, vr, 64 + (lane >> 4) * 16), of[dt]);
        }
        __syncthreads();
    }
    float inv[4];
    #pragma unroll
    for (int j = 0; j < 4; ++j) inv[j] = 1.f / l_run[j];
    #pragma unroll
    for (int dt = 0; dt < 4; ++dt)
        #pragma unroll
        for (int j = 0; j < 4; ++j)
            cob[(rowbase + r0 + w * 16 + qrow_lo + j) * C_ + h * 64 + dt * 16 + (lane & 15)] =
                (bf16)(of[dt][j] * inv[j]);
}

// ============ plucker MLP (pp), ds MLP, dn normalize ============
__global__ __launch_bounds__(256) void plucker_k(
    const float* __restrict__ pl,
    const float* __restrict__ w1, const float* __restrict__ b1,
    const float* __restrict__ w2, const float* __restrict__ b2,
    const float* __restrict__ w3, const float* __restrict__ b3,
    const float* __restrict__ dw1, const float* __restrict__ db1,
    const float* __restrict__ dw2, const float* __restrict__ db2,
    float* __restrict__ pp, float* __restrict__ ds, float* __restrict__ dn)
{
    const int row = blockIdx.x;
    const int t = threadIdx.x;
    __shared__ float plr[6];
    __shared__ float h1[256];
    __shared__ float h2[128];
    __shared__ float dh[64];
    if (t < 6) plr[t] = pl[(size_t)row * 6 + t];
    __syncthreads();
    {
        float a = b1[t];
        #pragma unroll
        for (int j = 0; j < 6; ++j) a = fmaf(plr[j], w1[j * 256 + t], a);
        h1[t] = gelu_f(a);
    }
    if (t < 64) {
        float d = db1[t];
        #pragma unroll
        for (int j = 0; j < 6; ++j) d = fmaf(plr[j], dw1[j * 64 + t], d);
        dh[t] = gelu_f(d);
    }
    if (t == 0) {
        float x = plr[0], y = plr[1], z = plr[2];
        float nrm = fmaxf(sqrtf(x * x + y * y + z * z), 1e-12f);
        dn[(size_t)row * 4 + 0] = x / nrm;
        dn[(size_t)row * 4 + 1] = y / nrm;
        dn[(size_t)row * 4 + 2] = z / nrm;
        dn[(size_t)row * 4 + 3] = 0.f;
    }
    __syncthreads();
    if (t < 128) {
        float a = b2[t];
        for (int j = 0; j < 256; ++j) a = fmaf(h1[j], w2[j * 128 + t], a);
        h2[t] = gelu_f(a);
    }
    if (t < 16) {
        float d = db2[t];
        for (int j = 0; j < 64; ++j) d = fmaf(dh[j], dw2[j * 16 + t], d);
        ds[(size_t)row * 16 + t] = tanhf(d);
    }
    __syncthreads();
    if (t < 128) {
        float a = b3[t];
        for (int j = 0; j < 128; ++j) a = fmaf(h2[j], w3[j * 128 + t], a);
        pp[(size_t)row * 128 + t] = a;
    }
}

// ============ spatial diffs ============
__global__ __launch_bounds__(256) void sd_k(const float* __restrict__ pp, float* __restrict__ sd)
{
    int g = blockIdx.x * 256 + threadIdx.x;
    if (g >= B_ * N_ * PP_) return;
    const int c = g & 127;
    const int rown = g >> 7;
    const int n = rown & (N_ - 1);
    const int xx = n & 31, yy = (n >> 5) & 31;
    const float cur = pp[g];
    const float hd = (xx < 31) ? fabsf(pp[g + PP_] - cur) : 0.f;
    const float vd = (yy < 31) ? fabsf(pp[g + 32 * PP_] - cur) : 0.f;
    sd[(size_t)rown * 256 + c] = hd;
    sd[(size_t)rown * 256 + 128 + c] = vd;
}

// ============ gb MLP ============
__global__ __launch_bounds__(256) void gb_k(
    const float* __restrict__ sd,
    const float* __restrict__ w1, const float* __restrict__ b1,
    const float* __restrict__ w2, const float* __restrict__ b2,
    float* __restrict__ gbv)
{
    const int row = blockIdx.x;
    const int t = threadIdx.x;
    __shared__ float s[256];
    __shared__ float h[512];
    s[t] = sd[(size_t)row * 256 + t];
    __syncthreads();
    #pragma unroll
    for (int o = 0; o < 2; ++o) {
        const int c = t + o * 256;
        float a = b1[c];
        for (int j = 0; j < 256; ++j) a = fmaf(s[j], w1[j * 512 + c], a);
        h[c] = gelu_f(a);
    }
    __syncthreads();
    if (t < 16) {
        float a = b2[t];
        for (int j = 0; j < 512; ++j) a = fmaf(h[j], w2[j * 16 + t], a);
        gbv[(size_t)row * 16 + t] = tanhf(a);
    }
}

// ============ concat [co_p(bf16) | pp(fp32->bf16)] ============
__global__ __launch_bounds__(256) void cat_k(
    const bf16* __restrict__ cop, const float* __restrict__ pp, bf16* __restrict__ cat)
{
    int g = blockIdx.x * 256 + threadIdx.x;
    if (g >= B_ * N_ * 1152 / 4) return;
    const int r = g / 288, c4 = (g % 288) * 4;
    bf16x4 o;
    if (c4 < 1024) {
        o = *reinterpret_cast<const bf16x4*>(cop + (size_t)r * 1024 + c4);
    } else {
        float4 v = *reinterpret_cast<const float4*>(pp + (size_t)r * 128 + (c4 - 1024));
        o = (bf16x4){(bf16)v.x, (bf16)v.y, (bf16)v.z, (bf16)v.w};
    }
    *reinterpret_cast<bf16x4*>(cat + (size_t)r * 1152 + c4) = o;
}

extern "C" void kernel_launch(void* const* d_in, const int* in_sizes, int n_in,
                              void* d_out, int out_size, void* d_ws, size_t ws_size,
                              hipStream_t stream)
{
    const float* x     = (const float*)d_in[0];
    const float* pl    = (const float*)d_in[1];
    const float* w_qkv = (const float*)d_in[2];
    const float* w_sp  = (const float*)d_in[3];
    const float* b_sp  = (const float*)d_in[4];
    const float* pl_w1 = (const float*)d_in[5];
    const float* pl_b1 = (const float*)d_in[6];
    const float* pl_w2 = (const float*)d_in[7];
    const float* pl_b2 = (const float*)d_in[8];
    const float* pl_w3 = (const float*)d_in[9];
    const float* pl_b3 = (const float*)d_in[10];
    const float* w_cq  = (const float*)d_in[11];
    const float* w_pk  = (const float*)d_in[12];
    const float* w_pv  = (const float*)d_in[13];
    const float* w_cp  = (const float*)d_in[14];
    const float* b_cp  = (const float*)d_in[15];
    const float* rdb   = (const float*)d_in[16];
    const float* ds_w1 = (const float*)d_in[17];
    const float* ds_b1 = (const float*)d_in[18];
    const float* ds_w2 = (const float*)d_in[19];
    const float* ds_b2 = (const float*)d_in[20];
    const float* gb_w1 = (const float*)d_in[21];
    const float* gb_b1 = (const float*)d_in[22];
    const float* gb_w2 = (const float*)d_in[23];
    const float* gb_b2 = (const float*)d_in[24];
    const float* rel_t = (const float*)d_in[25];
    const float* gfw1  = (const float*)d_in[26];
    const float* gfb1  = (const float*)d_in[27];
    const float* gfw2  = (const float*)d_in[28];
    const float* gfb2  = (const float*)d_in[29];

    char* W = (char*)d_ws;
    float* out = (float*)d_out;
    const size_t MB = 1ull << 20;

    bf16* qb     = (bf16*)(W + 0);           // 8MB ; cqb reuses
    bf16* kb     = (bf16*)(W + 8 * MB);      // 8MB ; ckb reuses
    bf16* vtb    = (bf16*)(W + 16 * MB);     // 8MB ; cvtb reuses
    bf16* cqb    = qb;
    bf16* ckb    = kb;
    bf16* cvtb   = vtb;
    bf16* xb     = (bf16*)(W + 24 * MB);     // 8MB
    bf16* wqkvT  = (bf16*)(W + 32 * MB);     // 6MB
    bf16* wspT   = (bf16*)(W + 38 * MB);     // 2MB
    bf16* wcqT   = (bf16*)(W + 40 * MB);     // 2MB
    bf16* wpkT   = (bf16*)(W + 42 * MB);     // 0.25MB
    bf16* wpvT   = (bf16*)(W + 42 * MB + 262144); // 0.25MB
    bf16* wcpT   = (bf16*)(W + 43 * MB);     // 2MB
    bf16* gfw1T  = (bf16*)(W + 45 * MB);     // 2.25MB
    bf16* gfw2T  = (bf16*)(W + 48 * MB);     // 2MB
    bf16* sab    = (bf16*)(W + 50 * MB);     // 8MB ; cob reuses
    bf16* cob    = sab;
    bf16* sapb   = (bf16*)(W + 58 * MB);     // 8MB ; copb reuses
    bf16* copb   = sapb;
    float* pp    = (float*)(W + 66 * MB);    // 2MB
    bf16* ppb    = (bf16*)(W + 68 * MB);     // 1MB
    float* sdb   = (float*)(W + 69 * MB);    // 4MB
    float* dsb   = (float*)(W + 73 * MB);    // 256KB
    float* dnb   = (float*)(W + 73 * MB + 262144);  // 64KB
    float* gbb   = (float*)(W + 73 * MB + 327680);  // 256KB
    float2* rtab = (float2*)(W + 74 * MB);   // 256KB
    bf16* catb   = (bf16*)(W + 75 * MB);     // 9MB
    bf16* hidb   = (bf16*)(W + 84 * MB);     // 8MB  -> 92MB total

    const dim3 blk(256);

    TJobs J;
    J.src[0] = w_qkv; J.dst[0] = wqkvT; J.K[0] = 1024; J.N[0] = 3072;
    J.src[1] = w_sp;  J.dst[1] = wspT;  J.K[1] = 1024; J.N[1] = 1024;
    J.src[2] = w_cq;  J.dst[2] = wcqT;  J.K[2] = 1024; J.N[2] = 1024;
    J.src[3] = w_pk;  J.dst[3] = wpkT;  J.K[3] = 128;  J.N[3] = 1024;
    J.src[4] = w_pv;  J.dst[4] = wpvT;  J.K[4] = 128;  J.N[4] = 1024;
    J.src[5] = w_cp;  J.dst[5] = wcpT;  J.K[5] = 1024; J.N[5] = 1024;
    J.src[6] = gfw1;  J.dst[6] = gfw1T; J.K[6] = 1152; J.N[6] = 1024;
    J.src[7] = gfw2;  J.dst[7] = gfw2T; J.K[7] = 1024; J.N[7] = 1024;
    tcast_k<<<dim3(96, 36, 8), blk, 0, stream>>>(J);
    cast_rm<<<4096, blk, 0, stream>>>(x, xb, 1048576);
    rope_tab_k<<<128, blk, 0, stream>>>(rtab);

    // qkv GEMM: fused rope + scale + bf16 head-major q,k + transposed v
    gemm_m<<<dim3(48, 32), blk, 0, stream>>>(xb, wqkvT, nullptr, nullptr,
        qb, kb, vtb, rtab, 4096, 3072, 1024, 2, 0, 0.125f);
    // self attention
    attn_self_m<<<1024, blk, 0, stream>>>(qb, kb, vtb, rel_t, sab);
    // self proj -> bf16 row-major
    gemm_m<<<dim3(16, 32), blk, 0, stream>>>(sab, wspT, b_sp, nullptr,
        sapb, nullptr, nullptr, nullptr, 4096, 1024, 1024, 1, 0, 1.f);
    // plucker MLPs
    plucker_k<<<4096, blk, 0, stream>>>(pl, pl_w1, pl_b1, pl_w2, pl_b2, pl_w3, pl_b3,
                                        ds_w1, ds_b1, ds_w2, ds_b2, pp, dsb, dnb);
    cast_rm<<<512, blk, 0, stream>>>(pp, ppb, 131072);
    // cq / ck (rope+head-major) / cv (transposed head-major)
    gemm_m<<<dim3(16, 32), blk, 0, stream>>>(sapb, wcqT, nullptr, nullptr,
        cqb, nullptr, nullptr, rtab, 4096, 1024, 1024, 3, 0, 0.125f);
    gemm_m<<<dim3(16, 32), blk, 0, stream>>>(ppb, wpkT, nullptr, nullptr,
        ckb, nullptr, nullptr, rtab, 4096, 1024, 128, 3, 0, 1.0f);
    gemm_m<<<dim3(16, 32), blk, 0, stream>>>(ppb, wpvT, nullptr, nullptr,
        cvtb, nullptr, nullptr, nullptr, 4096, 1024, 128, 4, 0, 1.f);
    // spatial diffs + gb MLP
    sd_k<<<2048, blk, 0, stream>>>(pp, sdb);
    gb_k<<<4096, blk, 0, stream>>>(sdb, gb_w1, gb_b1, gb_w2, gb_b2, gbb);
    // cross attention
    attn_cross_m<<<1024, blk, 0, stream>>>(cqb, ckb, cvtb, dnb, dsb, gbb, rdb, cob);
    // cross proj
    gemm_m<<<dim3(16, 32), blk, 0, stream>>>(cob, wcpT, b_cp, nullptr,
        copb, nullptr, nullptr, nullptr, 4096, 1024, 1024, 1, 0, 1.f);
    // concat + gfe
    cat_k<<<4608, blk, 0, stream>>>(copb, pp, catb);
    gemm_m<<<dim3(16, 32), blk, 0, stream>>>(catb, gfw1T, gfb1, nullptr,
        hidb, nullptr, nullptr, nullptr, 4096, 1024, 1152, 1, 1, 1.f);
    gemm_m<<<dim3(16, 32), blk, 0, stream>>>(hidb, gfw2T, gfb2, x,
        out, nullptr, nullptr, nullptr, 4096, 1024, 1024, 0, 0, 1.f);
}

// Round 4
// 470.051 us; speedup vs baseline: 7.4934x; 1.2105x over previous
//
#include <hip/hip_runtime.h>
#include <math.h>

#define B_ 4
#define N_ 1024
#define C_ 1024
#define NH_ 16
#define HD_ 64
#define PP_ 128

typedef __bf16 bf16;
typedef __attribute__((ext_vector_type(8))) __bf16 bf16x8;
typedef __attribute__((ext_vector_type(4))) __bf16 bf16x4;
typedef __attribute__((ext_vector_type(4))) float f32x4;

#define MFMA_BF16(a, b, c) __builtin_amdgcn_mfma_f32_16x16x32_bf16((a), (b), (c), 0, 0, 0)

__device__ __forceinline__ float gelu_f(float x) {
    return 0.5f * x * (1.0f + erff(x * 0.70710678118654752f));
}

__device__ __forceinline__ void gload16(const void* g, void* l) {
    __builtin_amdgcn_global_load_lds(
        (const __attribute__((address_space(1))) void*)g,
        (__attribute__((address_space(3))) void*)l, 16, 0, 0);
}

// stage a 64-row x 128B tile into LDS with XOR-swizzle (source pre-swizzled,
// LDS dest linear for global_load_lds). 256 threads, 2 chunks each.
__device__ __forceinline__ void stage64_swz(const bf16* __restrict__ g, int pitchB,
                                            bf16* lds, int t) {
    #pragma unroll
    for (int r = 0; r < 2; ++r) {
        int i = r * 256 + t;
        int row = i >> 3, c = i & 7;
        const char* src = (const char*)g + (size_t)row * pitchB + ((c ^ (row & 7)) << 4);
        bf16* dst = lds + (size_t)(r * 256 + (t & 192)) * 8;   // wave-uniform base
        gload16(src, dst);
    }
}

__device__ __forceinline__ bf16x8 lds8_swz(const bf16* lds, int row, int colb) {
    return *reinterpret_cast<const bf16x8*>(
        (const char*)lds + row * 128 + (colb ^ ((row & 7) << 4)));
}

// ============ rope table ============
__global__ __launch_bounds__(256) void rope_tab_k(float2* __restrict__ rt)
{
    int g = blockIdx.x * 256 + threadIdx.x;   // 32768
    const int n = g >> 5, i = g & 31;
    const float inv = powf(10000.0f, -(float)(2 * i) / 64.0f);
    const float ang = (float)n * inv;
    rt[g] = make_float2(cosf(ang), sinf(ang));
}

// ============ rel table transpose: relT[h][dy*63+dx] = rel_table[(dy*63+dx)*16+h] ============
__global__ __launch_bounds__(256) void relT_k(const float* __restrict__ rel_table,
                                              float* __restrict__ relT)
{
    int g = blockIdx.x * 256 + threadIdx.x;
    if (g >= 16 * 3969) return;
    int h = g / 3969, idx = g - h * 3969;
    relT[g] = rel_table[idx * 16 + h];
}

// ============ transpose-cast fp32 W[K,N] -> bf16 Wt[N,K] (8 jobs) ============
struct TJobs {
    const float* src[8];
    bf16* dst[8];
    int K[8];
    int N[8];
};

__global__ __launch_bounds__(256) void tcast_k(TJobs J)
{
    const int j = blockIdx.z;
    const int Kd = J.K[j], Nd = J.N[j];
    const int n0 = blockIdx.x * 32, k0 = blockIdx.y * 32;
    if (n0 >= Nd || k0 >= Kd) return;
    __shared__ float tl[32][33];
    const int t = threadIdx.x, tx = t & 31, ty = t >> 5;
    const float* src = J.src[j];
    bf16* dst = J.dst[j];
    #pragma unroll
    for (int r = 0; r < 4; ++r) {
        int kk = ty + r * 8;
        tl[kk][tx] = src[(size_t)(k0 + kk) * Nd + n0 + tx];
    }
    __syncthreads();
    #pragma unroll
    for (int r = 0; r < 4; ++r) {
        int nn = ty + r * 8;
        dst[(size_t)(n0 + nn) * Kd + k0 + tx] = (bf16)tl[tx][nn];
    }
}

// ============ elementwise cast fp32 -> bf16 ============
__global__ __launch_bounds__(256) void cast_rm(const float* __restrict__ in,
                                               bf16* __restrict__ out, int n4)
{
    int g = blockIdx.x * 256 + threadIdx.x;
    if (g >= n4) return;
    float4 v = reinterpret_cast<const float4*>(in)[g];
    bf16x4 o = {(bf16)v.x, (bf16)v.y, (bf16)v.z, (bf16)v.w};
    reinterpret_cast<bf16x4*>(out)[g] = o;
}

// ============ MFMA GEMM with fused epilogues, 2-phase double-buffered ============
__global__ __launch_bounds__(256) void gemm_m(
    const bf16* __restrict__ A, const bf16* __restrict__ Bt,
    const float* __restrict__ bias, const float* __restrict__ resid,
    void* __restrict__ out0, void* __restrict__ out1, void* __restrict__ out2,
    const float2* __restrict__ rtab,
    int M, int N, int K, int epi, int act_gelu, float scale)
{
    __shared__ bf16 As[2][128 * 32];
    __shared__ bf16 Bs[2][64 * 32];
    const int t = threadIdx.x;
    const int w = t >> 6, lane = t & 63;
    const int row0 = blockIdx.y * 128, col0 = blockIdx.x * 64;
    const int wm = w >> 1, wn = w & 1;
    f32x4 acc[4][2];
    #pragma unroll
    for (int mi = 0; mi < 4; ++mi)
        #pragma unroll
        for (int ni = 0; ni < 2; ++ni)
            acc[mi][ni] = (f32x4){0.f, 0.f, 0.f, 0.f};

    #define STAGE_AB(k0, buf)                                                        \
        {                                                                            \
            _Pragma("unroll")                                                        \
            for (int r = 0; r < 2; ++r) {                                            \
                int c = r * 256 + t;                                                 \
                const bf16* src = A + (size_t)(row0 + (c >> 2)) * K + (k0) + (c & 3) * 8; \
                gload16(src, As[buf] + (size_t)(r * 256 + w * 64) * 8);              \
            }                                                                        \
            const bf16* srcb = Bt + (size_t)(col0 + (t >> 2)) * K + (k0) + (t & 3) * 8; \
            gload16(srcb, Bs[buf] + (size_t)(w * 64) * 8);                           \
        }

    STAGE_AB(0, 0);
    __syncthreads();
    int cur = 0;
    const int nk = K >> 5;
    for (int kk = 0; kk < nk; ++kk) {
        if (kk + 1 < nk) STAGE_AB((kk + 1) * 32, cur ^ 1);
        bf16x8 af[4], bfv[2];
        #pragma unroll
        for (int mi = 0; mi < 4; ++mi)
            af[mi] = *reinterpret_cast<const bf16x8*>(
                As[cur] + (wm * 64 + mi * 16 + (lane & 15)) * 32 + (lane >> 4) * 8);
        #pragma unroll
        for (int ni = 0; ni < 2; ++ni)
            bfv[ni] = *reinterpret_cast<const bf16x8*>(
                Bs[cur] + (wn * 32 + ni * 16 + (lane & 15)) * 32 + (lane >> 4) * 8);
        #pragma unroll
        for (int mi = 0; mi < 4; ++mi)
            #pragma unroll
            for (int ni = 0; ni < 2; ++ni)
                acc[mi][ni] = MFMA_BF16(af[mi], bfv[ni], acc[mi][ni]);
        __syncthreads();
        cur ^= 1;
    }
    #undef STAGE_AB

    #pragma unroll
    for (int mi = 0; mi < 4; ++mi) {
        #pragma unroll
        for (int ni = 0; ni < 2; ++ni) {
            const int col = col0 + wn * 32 + ni * 16 + (lane & 15);
            if (epi <= 1) {
                const float bv = bias ? bias[col] : 0.f;
                #pragma unroll
                for (int j = 0; j < 4; ++j) {
                    const int row = row0 + wm * 64 + mi * 16 + (lane >> 4) * 4 + j;
                    float v = acc[mi][ni][j] + bv;
                    if (act_gelu) v = gelu_f(v);
                    if (epi == 0) {
                        if (resid) v += resid[(size_t)row * N + col];
                        ((float*)out0)[(size_t)row * N + col] = v;
                    } else {
                        ((bf16*)out0)[(size_t)row * N + col] = (bf16)v;
                    }
                }
            } else if (epi == 2) {
                const int reg = col >> 10;         // 0=q 1=k 2=v
                const int h = (col >> 6) & 15, d = col & 63;
                if (reg <= 1) {
                    bf16* dst = reg == 0 ? (bf16*)out0 : (bf16*)out1;
                    const float sc = reg == 0 ? scale : 1.0f;
                    #pragma unroll
                    for (int j = 0; j < 4; ++j) {
                        const int row = row0 + wm * 64 + mi * 16 + (lane >> 4) * 4 + j;
                        const int b = row >> 10, n = row & 1023;
                        float v = acc[mi][ni][j];
                        float pv = __shfl_xor(v, 1);
                        float2 cs = rtab[(n << 5) + (d >> 1)];
                        float o = (d & 1) == 0 ? v * cs.x - pv * cs.y
                                               : v * cs.x + pv * cs.y;
                        dst[((size_t)((b * 16 + h) * 1024 + n)) * 64 + d] = (bf16)(o * sc);
                    }
                } else {
                    bf16x4 o4;
                    #pragma unroll
                    for (int j = 0; j < 4; ++j) o4[j] = (bf16)acc[mi][ni][j];
                    const int row = row0 + wm * 64 + mi * 16 + (lane >> 4) * 4;
                    const int b = row >> 10, n = row & 1023;
                    *reinterpret_cast<bf16x4*>(
                        (bf16*)out2 + ((size_t)((b * 16 + h) * 64 + d)) * 1024 + n) = o4;
                }
            } else if (epi == 3) {
                const int h = (col >> 6) & 15, d = col & 63;
                #pragma unroll
                for (int j = 0; j < 4; ++j) {
                    const int row = row0 + wm * 64 + mi * 16 + (lane >> 4) * 4 + j;
                    const int b = row >> 10, n = row & 1023;
                    float v = acc[mi][ni][j];
                    float pv = __shfl_xor(v, 1);
                    float2 cs = rtab[(n << 5) + (d >> 1)];
                    float o = (d & 1) == 0 ? v * cs.x - pv * cs.y
                                           : v * cs.x + pv * cs.y;
                    ((bf16*)out0)[((size_t)((b * 16 + h) * 1024 + n)) * 64 + d] = (bf16)(o * scale);
                }
            } else {  // epi == 4: transposed head-major
                const int h = (col >> 6) & 15, d = col & 63;
                bf16x4 o4;
                #pragma unroll
                for (int j = 0; j < 4; ++j) o4[j] = (bf16)acc[mi][ni][j];
                const int row = row0 + wm * 64 + mi * 16 + (lane >> 4) * 4;
                const int b = row >> 10, n = row & 1023;
                *reinterpret_cast<bf16x4*>(
                    (bf16*)out0 + ((size_t)((b * 16 + h) * 64 + d)) * 1024 + n) = o4;
            }
        }
    }
}

// ============ XCD-aware block decomposition for attention ============
__device__ __forceinline__ void attn_bid(int bid, int& bh, int& r0t) {
    const int xcd = bid & 7, s = bid >> 3;
    bh = (s >> 4) * 8 + xcd;   // 0..63
    r0t = s & 15;
}

// ============ MFMA flash self-attention, 2-phase pipelined ============
__global__ __launch_bounds__(256) void attn_self_m(
    const bf16* __restrict__ qb, const bf16* __restrict__ kb, const bf16* __restrict__ vtb,
    const float* __restrict__ relT, bf16* __restrict__ sab)
{
    __shared__ bf16 Ks[2][64 * 64];
    __shared__ bf16 Vs[2][64 * 64];
    __shared__ bf16 Ps[64 * 72];
    __shared__ float relb[2][192];
    const int t = threadIdx.x, w = t >> 6, lane = t & 63;
    int bh, r0t;
    attn_bid(blockIdx.x, bh, r0t);
    const int b = bh >> 4, h = bh & 15, r0 = r0t * 64;
    const float* relTh = relT + h * 3969;
    const int y0 = r0 >> 5;

    // stage Q into Ks[0] (temp), pull A-frags
    stage64_swz(qb + ((size_t)bh * 1024 + r0) * 64, 128, Ks[0], t);
    __syncthreads();
    bf16x8 aq[2];
    {
        const int qr = w * 16 + (lane & 15);
        aq[0] = lds8_swz(Ks[0], qr, (lane >> 4) * 16);
        aq[1] = lds8_swz(Ks[0], qr, 64 + (lane >> 4) * 16);
    }
    __syncthreads();
    // stage tile 0
    stage64_swz(kb + (size_t)bh * 65536, 128, Ks[0], t);
    stage64_swz(vtb + (size_t)bh * 65536, 2048, Vs[0], t);
    if (t < 192) {
        relb[0][t] = relTh[(y0 + 30 + (t >> 6)) * 63 + min(t & 63, 62)];
    }

    float m_run[4], l_run[4];
    f32x4 of[4];
    #pragma unroll
    for (int j = 0; j < 4; ++j) { m_run[j] = -3e38f; l_run[j] = 0.f; }
    #pragma unroll
    for (int dt = 0; dt < 4; ++dt) of[dt] = (f32x4){0.f, 0.f, 0.f, 0.f};

    const int qrow_lo = (lane >> 4) * 4;
    int dybase[4];
    #pragma unroll
    for (int j = 0; j < 4; ++j) {
        int qg = r0 + w * 16 + qrow_lo + j;
        dybase[j] = (((qg >> 5) - y0) + 1) * 64 + (qg & 31) + 31;
    }
    __syncthreads();

    int cur = 0;
    for (int mt = 0; mt < 16; ++mt) {
        if (mt < 15) {  // prefetch next tile (drained by end-of-iter barrier)
            stage64_swz(kb + (size_t)bh * 65536 + (size_t)(mt + 1) * 64 * 64, 128, Ks[cur ^ 1], t);
            stage64_swz(vtb + (size_t)bh * 65536 + (size_t)(mt + 1) * 64, 2048, Vs[cur ^ 1], t);
            if (t < 192) {
                relb[cur ^ 1][t] = relTh[(y0 - 2 * (mt + 1) + 30 + (t >> 6)) * 63 + min(t & 63, 62)];
            }
        }
        f32x4 sf[4];
        __builtin_amdgcn_s_setprio(1);
        #pragma unroll
        for (int ct = 0; ct < 4; ++ct) {
            const int kr = ct * 16 + (lane & 15);
            f32x4 a = (f32x4){0.f, 0.f, 0.f, 0.f};
            a = MFMA_BF16(aq[0], lds8_swz(Ks[cur], kr, (lane >> 4) * 16), a);
            a = MFMA_BF16(aq[1], lds8_swz(Ks[cur], kr, 64 + (lane >> 4) * 16), a);
            sf[ct] = a;
        }
        __builtin_amdgcn_s_setprio(0);
        float p[4][4], mx[4];
        #pragma unroll
        for (int j = 0; j < 4; ++j) mx[j] = -3e38f;
        #pragma unroll
        for (int ct = 0; ct < 4; ++ct) {
            const int xm = (ct & 1) * 16 + (lane & 15);
            const int ro = (ct >> 1) * 64 + xm;
            #pragma unroll
            for (int j = 0; j < 4; ++j) {
                float s = sf[ct][j] + relb[cur][dybase[j] - ro];
                p[ct][j] = s;
                mx[j] = fmaxf(mx[j], s);
            }
        }
        #pragma unroll
        for (int d = 1; d < 16; d <<= 1)
            #pragma unroll
            for (int j = 0; j < 4; ++j) mx[j] = fmaxf(mx[j], __shfl_xor(mx[j], d));
        float alpha[4], rs[4];
        #pragma unroll
        for (int j = 0; j < 4; ++j) {
            float mn = fmaxf(m_run[j], mx[j]);
            alpha[j] = __expf(m_run[j] - mn);
            m_run[j] = mn;
            rs[j] = 0.f;
        }
        #pragma unroll
        for (int ct = 0; ct < 4; ++ct)
            #pragma unroll
            for (int j = 0; j < 4; ++j) {
                float e = __expf(p[ct][j] - m_run[j]);
                p[ct][j] = e;
                rs[j] += e;
            }
        #pragma unroll
        for (int d = 1; d < 16; d <<= 1)
            #pragma unroll
            for (int j = 0; j < 4; ++j) rs[j] += __shfl_xor(rs[j], d);
        #pragma unroll
        for (int j = 0; j < 4; ++j) l_run[j] = l_run[j] * alpha[j] + rs[j];
        #pragma unroll
        for (int dt = 0; dt < 4; ++dt)
            #pragma unroll
            for (int j = 0; j < 4; ++j) of[dt][j] *= alpha[j];
        #pragma unroll
        for (int ct = 0; ct < 4; ++ct)
            #pragma unroll
            for (int j = 0; j < 4; ++j)
                Ps[(w * 16 + qrow_lo + j) * 72 + ct * 16 + (lane & 15)] = (bf16)p[ct][j];
        asm volatile("s_waitcnt lgkmcnt(0)" ::: "memory");
        __builtin_amdgcn_sched_barrier(0);
        bf16x8 ap0 = *reinterpret_cast<const bf16x8*>(Ps + (w * 16 + (lane & 15)) * 72 + (lane >> 4) * 8);
        bf16x8 ap1 = *reinterpret_cast<const bf16x8*>(Ps + (w * 16 + (lane & 15)) * 72 + 32 + (lane >> 4) * 8);
        __builtin_amdgcn_s_setprio(1);
        #pragma unroll
        for (int dt = 0; dt < 4; ++dt) {
            const int vr = dt * 16 + (lane & 15);
            of[dt] = MFMA_BF16(ap0, lds8_swz(Vs[cur], vr, (lane >> 4) * 16), of[dt]);
            of[dt] = MFMA_BF16(ap1, lds8_swz(Vs[cur], vr, 64 + (lane >> 4) * 16), of[dt]);
        }
        __builtin_amdgcn_s_setprio(0);
        __syncthreads();
        cur ^= 1;
    }
    float inv[4];
    #pragma unroll
    for (int j = 0; j < 4; ++j) inv[j] = 1.f / l_run[j];
    #pragma unroll
    for (int dt = 0; dt < 4; ++dt)
        #pragma unroll
        for (int j = 0; j < 4; ++j)
            sab[((size_t)(b * N_ + r0 + w * 16 + qrow_lo + j)) * C_ + h * 64 + dt * 16 + (lane & 15)] =
                (bf16)(of[dt][j] * inv[j]);
}

// ============ MFMA flash cross-attention, 2-phase pipelined ============
__global__ __launch_bounds__(256) void attn_cross_m(
    const bf16* __restrict__ cq, const bf16* __restrict__ ck, const bf16* __restrict__ cvt,
    const float* __restrict__ dn, const float* __restrict__ ds, const float* __restrict__ gb,
    const float* __restrict__ rdb, bf16* __restrict__ cob)
{
    __shared__ bf16 Ks[2][64 * 64];
    __shared__ bf16 Vs[2][64 * 64];
    __shared__ bf16 Ps[64 * 72];
    __shared__ float4 dnms[2][64];
    const int t = threadIdx.x, w = t >> 6, lane = t & 63;
    int bh, r0t;
    attn_bid(blockIdx.x, bh, r0t);
    const int b = bh >> 4, h = bh & 15, r0 = r0t * 64;
    const size_t rowbase = (size_t)b * N_;
    const float rdbh = rdb[h];

    stage64_swz(cq + ((size_t)bh * 1024 + r0) * 64, 128, Ks[0], t);
    __syncthreads();
    bf16x8 aq[2];
    {
        const int qr = w * 16 + (lane & 15);
        aq[0] = lds8_swz(Ks[0], qr, (lane >> 4) * 16);
        aq[1] = lds8_swz(Ks[0], qr, 64 + (lane >> 4) * 16);
    }
    __syncthreads();
    stage64_swz(ck + (size_t)bh * 65536, 128, Ks[0], t);
    stage64_swz(cvt + (size_t)bh * 65536, 2048, Vs[0], t);
    if (t < 64) {
        float4 d4 = *reinterpret_cast<const float4*>(dn + (rowbase + t) * 4);
        dnms[0][t] = make_float4(d4.x, d4.y, d4.z, gb[(rowbase + t) * NH_ + h]);
    }

    const int qrow_lo = (lane >> 4) * 4;
    float dqx[4], dqy[4], dqz[4], dsr[4];
    #pragma unroll
    for (int j = 0; j < 4; ++j) {
        const size_t rg = rowbase + r0 + w * 16 + qrow_lo + j;
        dqx[j] = dn[rg * 4 + 0];
        dqy[j] = dn[rg * 4 + 1];
        dqz[j] = dn[rg * 4 + 2];
        dsr[j] = 1.0f + ds[rg * NH_ + h];
    }

    float m_run[4], l_run[4];
    f32x4 of[4];
    #pragma unroll
    for (int j = 0; j < 4; ++j) { m_run[j] = -3e38f; l_run[j] = 0.f; }
    #pragma unroll
    for (int dt = 0; dt < 4; ++dt) of[dt] = (f32x4){0.f, 0.f, 0.f, 0.f};
    __syncthreads();

    int cur = 0;
    for (int mt = 0; mt < 16; ++mt) {
        if (mt < 15) {
            stage64_swz(ck + (size_t)bh * 65536 + (size_t)(mt + 1) * 64 * 64, 128, Ks[cur ^ 1], t);
            stage64_swz(cvt + (size_t)bh * 65536 + (size_t)(mt + 1) * 64, 2048, Vs[cur ^ 1], t);
            if (t < 64) {
                float4 d4 = *reinterpret_cast<const float4*>(dn + (rowbase + (mt + 1) * 64 + t) * 4);
                dnms[cur ^ 1][t] = make_float4(d4.x, d4.y, d4.z, gb[(rowbase + (mt + 1) * 64 + t) * NH_ + h]);
            }
        }
        f32x4 sf[4];
        __builtin_amdgcn_s_setprio(1);
        #pragma unroll
        for (int ct = 0; ct < 4; ++ct) {
            const int kr = ct * 16 + (lane & 15);
            f32x4 a = (f32x4){0.f, 0.f, 0.f, 0.f};
            a = MFMA_BF16(aq[0], lds8_swz(Ks[cur], kr, (lane >> 4) * 16), a);
            a = MFMA_BF16(aq[1], lds8_swz(Ks[cur], kr, 64 + (lane >> 4) * 16), a);
            sf[ct] = a;
        }
        __builtin_amdgcn_s_setprio(0);
        float p[4][4], mx[4];
        #pragma unroll
        for (int j = 0; j < 4; ++j) mx[j] = -3e38f;
        #pragma unroll
        for (int ct = 0; ct < 4; ++ct) {
            const float4 dm = dnms[cur][ct * 16 + (lane & 15)];
            #pragma unroll
            for (int j = 0; j < 4; ++j) {
                float sim = dqx[j] * dm.x + dqy[j] * dm.y + dqz[j] * dm.z;
                float s = (sf[ct][j] + sim * rdbh) * dsr[j] + dm.w;
                p[ct][j] = s;
                mx[j] = fmaxf(mx[j], s);
            }
        }
        #pragma unroll
        for (int d = 1; d < 16; d <<= 1)
            #pragma unroll
            for (int j = 0; j < 4; ++j) mx[j] = fmaxf(mx[j], __shfl_xor(mx[j], d));
        float alpha[4], rs[4];
        #pragma unroll
        for (int j = 0; j < 4; ++j) {
            float mn = fmaxf(m_run[j], mx[j]);
            alpha[j] = __expf(m_run[j] - mn);
            m_run[j] = mn;
            rs[j] = 0.f;
        }
        #pragma unroll
        for (int ct = 0; ct < 4; ++ct)
            #pragma unroll
            for (int j = 0; j < 4; ++j) {
                float e = __expf(p[ct][j] - m_run[j]);
                p[ct][j] = e;
                rs[j] += e;
            }
        #pragma unroll
        for (int d = 1; d < 16; d <<= 1)
            #pragma unroll
            for (int j = 0; j < 4; ++j) rs[j] += __shfl_xor(rs[j], d);
        #pragma unroll
        for (int j = 0; j < 4; ++j) l_run[j] = l_run[j] * alpha[j] + rs[j];
        #pragma unroll
        for (int dt = 0; dt < 4; ++dt)
            #pragma unroll
            for (int j = 0; j < 4; ++j) of[dt][j] *= alpha[j];
        #pragma unroll
        for (int ct = 0; ct < 4; ++ct)
            #pragma unroll
            for (int j = 0; j < 4; ++j)
                Ps[(w * 16 + qrow_lo + j) * 72 + ct * 16 + (lane & 15)] = (bf16)p[ct][j];
        asm volatile("s_waitcnt lgkmcnt(0)" ::: "memory");
        __builtin_amdgcn_sched_barrier(0);
        bf16x8 ap0 = *reinterpret_cast<const bf16x8*>(Ps + (w * 16 + (lane & 15)) * 72 + (lane >> 4) * 8);
        bf16x8 ap1 = *reinterpret_cast<const bf16x8*>(Ps + (w * 16 + (lane & 15)) * 72 + 32 + (lane >> 4) * 8);
        __builtin_amdgcn_s_setprio(1);
        #pragma unroll
        for (int dt = 0; dt < 4; ++dt) {
            const int vr = dt * 16 + (lane & 15);
            of[dt] = MFMA_BF16(ap0, lds8_swz(Vs[cur], vr, (lane >> 4) * 16), of[dt]);
            of[dt] = MFMA_BF16(ap1, lds8_swz(Vs[cur], vr, 64 + (lane >> 4) * 16), of[dt]);
        }
        __builtin_amdgcn_s_setprio(0);
        __syncthreads();
        cur ^= 1;
    }
    float inv[4];
    #pragma unroll
    for (int j = 0; j < 4; ++j) inv[j] = 1.f / l_run[j];
    #pragma unroll
    for (int dt = 0; dt < 4; ++dt)
        #pragma unroll
        for (int j = 0; j < 4; ++j)
            cob[(rowbase + r0 + w * 16 + qrow_lo + j) * C_ + h * 64 + dt * 16 + (lane & 15)] =
                (bf16)(of[dt][j] * inv[j]);
}

// ============ plucker MLP (pp), ds MLP, dn normalize ============
__global__ __launch_bounds__(256) void plucker_k(
    const float* __restrict__ pl,
    const float* __restrict__ w1, const float* __restrict__ b1,
    const float* __restrict__ w2, const float* __restrict__ b2,
    const float* __restrict__ w3, const float* __restrict__ b3,
    const float* __restrict__ dw1, const float* __restrict__ db1,
    const float* __restrict__ dw2, const float* __restrict__ db2,
    float* __restrict__ pp, float* __restrict__ ds, float* __restrict__ dn)
{
    const int row = blockIdx.x;
    const int t = threadIdx.x;
    __shared__ float plr[6];
    __shared__ float h1[256];
    __shared__ float h2[128];
    __shared__ float dh[64];
    if (t < 6) plr[t] = pl[(size_t)row * 6 + t];
    __syncthreads();
    {
        float a = b1[t];
        #pragma unroll
        for (int j = 0; j < 6; ++j) a = fmaf(plr[j], w1[j * 256 + t], a);
        h1[t] = gelu_f(a);
    }
    if (t < 64) {
        float d = db1[t];
        #pragma unroll
        for (int j = 0; j < 6; ++j) d = fmaf(plr[j], dw1[j * 64 + t], d);
        dh[t] = gelu_f(d);
    }
    if (t == 0) {
        float x = plr[0], y = plr[1], z = plr[2];
        float nrm = fmaxf(sqrtf(x * x + y * y + z * z), 1e-12f);
        dn[(size_t)row * 4 + 0] = x / nrm;
        dn[(size_t)row * 4 + 1] = y / nrm;
        dn[(size_t)row * 4 + 2] = z / nrm;
        dn[(size_t)row * 4 + 3] = 0.f;
    }
    __syncthreads();
    if (t < 128) {
        float a = b2[t];
        for (int j = 0; j < 256; ++j) a = fmaf(h1[j], w2[j * 128 + t], a);
        h2[t] = gelu_f(a);
    }
    if (t < 16) {
        float d = db2[t];
        for (int j = 0; j < 64; ++j) d = fmaf(dh[j], dw2[j * 16 + t], d);
        ds[(size_t)row * 16 + t] = tanhf(d);
    }
    __syncthreads();
    if (t < 128) {
        float a = b3[t];
        for (int j = 0; j < 128; ++j) a = fmaf(h2[j], w3[j * 128 + t], a);
        pp[(size_t)row * 128 + t] = a;
    }
}

// ============ spatial diffs ============
__global__ __launch_bounds__(256) void sd_k(const float* __restrict__ pp, float* __restrict__ sd)
{
    int g = blockIdx.x * 256 + threadIdx.x;
    if (g >= B_ * N_ * PP_) return;
    const int c = g & 127;
    const int rown = g >> 7;
    const int n = rown & (N_ - 1);
    const int xx = n & 31, yy = (n >> 5) & 31;
    const float cur = pp[g];
    const float hd = (xx < 31) ? fabsf(pp[g + PP_] - cur) : 0.f;
    const float vd = (yy < 31) ? fabsf(pp[g + 32 * PP_] - cur) : 0.f;
    sd[(size_t)rown * 256 + c] = hd;
    sd[(size_t)rown * 256 + 128 + c] = vd;
}

// ============ gb MLP ============
__global__ __launch_bounds__(256) void gb_k(
    const float* __restrict__ sd,
    const float* __restrict__ w1, const float* __restrict__ b1,
    const float* __restrict__ w2, const float* __restrict__ b2,
    float* __restrict__ gbv)
{
    const int row = blockIdx.x;
    const int t = threadIdx.x;
    __shared__ float s[256];
    __shared__ float h[512];
    s[t] = sd[(size_t)row * 256 + t];
    __syncthreads();
    #pragma unroll
    for (int o = 0; o < 2; ++o) {
        const int c = t + o * 256;
        float a = b1[c];
        for (int j = 0; j < 256; ++j) a = fmaf(s[j], w1[j * 512 + c], a);
        h[c] = gelu_f(a);
    }
    __syncthreads();
    if (t < 16) {
        float a = b2[t];
        for (int j = 0; j < 512; ++j) a = fmaf(h[j], w2[j * 16 + t], a);
        gbv[(size_t)row * 16 + t] = tanhf(a);
    }
}

// ============ concat [co_p(bf16) | pp(fp32->bf16)] ============
__global__ __launch_bounds__(256) void cat_k(
    const bf16* __restrict__ cop, const float* __restrict__ pp, bf16* __restrict__ cat)
{
    int g = blockIdx.x * 256 + threadIdx.x;
    if (g >= B_ * N_ * 1152 / 4) return;
    const int r = g / 288, c4 = (g % 288) * 4;
    bf16x4 o;
    if (c4 < 1024) {
        o = *reinterpret_cast<const bf16x4*>(cop + (size_t)r * 1024 + c4);
    } else {
        float4 v = *reinterpret_cast<const float4*>(pp + (size_t)r * 128 + (c4 - 1024));
        o = (bf16x4){(bf16)v.x, (bf16)v.y, (bf16)v.z, (bf16)v.w};
    }
    *reinterpret_cast<bf16x4*>(cat + (size_t)r * 1152 + c4) = o;
}

extern "C" void kernel_launch(void* const* d_in, const int* in_sizes, int n_in,
                              void* d_out, int out_size, void* d_ws, size_t ws_size,
                              hipStream_t stream)
{
    const float* x     = (const float*)d_in[0];
    const float* pl    = (const float*)d_in[1];
    const float* w_qkv = (const float*)d_in[2];
    const float* w_sp  = (const float*)d_in[3];
    const float* b_sp  = (const float*)d_in[4];
    const float* pl_w1 = (const float*)d_in[5];
    const float* pl_b1 = (const float*)d_in[6];
    const float* pl_w2 = (const float*)d_in[7];
    const float* pl_b2 = (const float*)d_in[8];
    const float* pl_w3 = (const float*)d_in[9];
    const float* pl_b3 = (const float*)d_in[10];
    const float* w_cq  = (const float*)d_in[11];
    const float* w_pk  = (const float*)d_in[12];
    const float* w_pv  = (const float*)d_in[13];
    const float* w_cp  = (const float*)d_in[14];
    const float* b_cp  = (const float*)d_in[15];
    const float* rdb   = (const float*)d_in[16];
    const float* ds_w1 = (const float*)d_in[17];
    const float* ds_b1 = (const float*)d_in[18];
    const float* ds_w2 = (const float*)d_in[19];
    const float* ds_b2 = (const float*)d_in[20];
    const float* gb_w1 = (const float*)d_in[21];
    const float* gb_b1 = (const float*)d_in[22];
    const float* gb_w2 = (const float*)d_in[23];
    const float* gb_b2 = (const float*)d_in[24];
    const float* rel_t = (const float*)d_in[25];
    const float* gfw1  = (const float*)d_in[26];
    const float* gfb1  = (const float*)d_in[27];
    const float* gfw2  = (const float*)d_in[28];
    const float* gfb2  = (const float*)d_in[29];

    char* W = (char*)d_ws;
    float* out = (float*)d_out;
    const size_t MB = 1ull << 20;

    bf16* qb     = (bf16*)(W + 0);           // 8MB ; cqb reuses
    bf16* kb     = (bf16*)(W + 8 * MB);      // 8MB ; ckb reuses
    bf16* vtb    = (bf16*)(W + 16 * MB);     // 8MB ; cvtb reuses
    bf16* cqb    = qb;
    bf16* ckb    = kb;
    bf16* cvtb   = vtb;
    bf16* xb     = (bf16*)(W + 24 * MB);     // 8MB
    bf16* wqkvT  = (bf16*)(W + 32 * MB);     // 6MB
    bf16* wspT   = (bf16*)(W + 38 * MB);     // 2MB
    bf16* wcqT   = (bf16*)(W + 40 * MB);     // 2MB
    bf16* wpkT   = (bf16*)(W + 42 * MB);     // 0.25MB
    bf16* wpvT   = (bf16*)(W + 42 * MB + 262144); // 0.25MB
    bf16* wcpT   = (bf16*)(W + 43 * MB);     // 2MB
    bf16* gfw1T  = (bf16*)(W + 45 * MB);     // 2.25MB
    bf16* gfw2T  = (bf16*)(W + 48 * MB);     // 2MB
    bf16* sab    = (bf16*)(W + 50 * MB);     // 8MB ; cob reuses
    bf16* cob    = sab;
    bf16* sapb   = (bf16*)(W + 58 * MB);     // 8MB ; copb reuses
    bf16* copb   = sapb;
    float* pp    = (float*)(W + 66 * MB);    // 2MB
    bf16* ppb    = (bf16*)(W + 68 * MB);     // 1MB
    float* sdb   = (float*)(W + 69 * MB);    // 4MB
    float* dsb   = (float*)(W + 73 * MB);    // 256KB
    float* dnb   = (float*)(W + 73 * MB + 262144);  // 64KB
    float* gbb   = (float*)(W + 73 * MB + 327680);  // 256KB
    float2* rtab = (float2*)(W + 74 * MB);   // 256KB
    float* relTb = (float*)(W + 74 * MB + 262144);  // 254KB
    bf16* catb   = (bf16*)(W + 75 * MB);     // 9MB
    bf16* hidb   = (bf16*)(W + 84 * MB);     // 8MB  -> 92MB total

    const dim3 blk(256);

    TJobs J;
    J.src[0] = w_qkv; J.dst[0] = wqkvT; J.K[0] = 1024; J.N[0] = 3072;
    J.src[1] = w_sp;  J.dst[1] = wspT;  J.K[1] = 1024; J.N[1] = 1024;
    J.src[2] = w_cq;  J.dst[2] = wcqT;  J.K[2] = 1024; J.N[2] = 1024;
    J.src[3] = w_pk;  J.dst[3] = wpkT;  J.K[3] = 128;  J.N[3] = 1024;
    J.src[4] = w_pv;  J.dst[4] = wpvT;  J.K[4] = 128;  J.N[4] = 1024;
    J.src[5] = w_cp;  J.dst[5] = wcpT;  J.K[5] = 1024; J.N[5] = 1024;
    J.src[6] = gfw1;  J.dst[6] = gfw1T; J.K[6] = 1152; J.N[6] = 1024;
    J.src[7] = gfw2;  J.dst[7] = gfw2T; J.K[7] = 1024; J.N[7] = 1024;
    tcast_k<<<dim3(96, 36, 8), blk, 0, stream>>>(J);
    cast_rm<<<4096, blk, 0, stream>>>(x, xb, 1048576);
    rope_tab_k<<<128, blk, 0, stream>>>(rtab);
    relT_k<<<249, blk, 0, stream>>>(rel_t, relTb);

    // qkv GEMM: fused rope + scale + bf16 head-major q,k + transposed v
    gemm_m<<<dim3(48, 32), blk, 0, stream>>>(xb, wqkvT, nullptr, nullptr,
        qb, kb, vtb, rtab, 4096, 3072, 1024, 2, 0, 0.125f);
    // self attention
    attn_self_m<<<1024, blk, 0, stream>>>(qb, kb, vtb, relTb, sab);
    // self proj -> bf16 row-major
    gemm_m<<<dim3(16, 32), blk, 0, stream>>>(sab, wspT, b_sp, nullptr,
        sapb, nullptr, nullptr, nullptr, 4096, 1024, 1024, 1, 0, 1.f);
    // plucker MLPs
    plucker_k<<<4096, blk, 0, stream>>>(pl, pl_w1, pl_b1, pl_w2, pl_b2, pl_w3, pl_b3,
                                        ds_w1, ds_b1, ds_w2, ds_b2, pp, dsb, dnb);
    cast_rm<<<512, blk, 0, stream>>>(pp, ppb, 131072);
    // cq / ck (rope+head-major) / cv (transposed head-major)
    gemm_m<<<dim3(16, 32), blk, 0, stream>>>(sapb, wcqT, nullptr, nullptr,
        cqb, nullptr, nullptr, rtab, 4096, 1024, 1024, 3, 0, 0.125f);
    gemm_m<<<dim3(16, 32), blk, 0, stream>>>(ppb, wpkT, nullptr, nullptr,
        ckb, nullptr, nullptr, rtab, 4096, 1024, 128, 3, 0, 1.0f);
    gemm_m<<<dim3(16, 32), blk, 0, stream>>>(ppb, wpvT, nullptr, nullptr,
        cvtb, nullptr, nullptr, nullptr, 4096, 1024, 128, 4, 0, 1.f);
    // spatial diffs + gb MLP
    sd_k<<<2048, blk, 0, stream>>>(pp, sdb);
    gb_k<<<4096, blk, 0, stream>>>(sdb, gb_w1, gb_b1, gb_w2, gb_b2, gbb);
    // cross attention
    attn_cross_m<<<1024, blk, 0, stream>>>(cqb, ckb, cvtb, dnb, dsb, gbb, rdb, cob);
    // cross proj
    gemm_m<<<dim3(16, 32), blk, 0, stream>>>(cob, wcpT, b_cp, nullptr,
        copb, nullptr, nullptr, nullptr, 4096, 1024, 1024, 1, 0, 1.f);
    // concat + gfe
    cat_k<<<4608, blk, 0, stream>>>(copb, pp, catb);
    gemm_m<<<dim3(16, 32), blk, 0, stream>>>(catb, gfw1T, gfb1, nullptr,
        hidb, nullptr, nullptr, nullptr, 4096, 1024, 1152, 1, 1, 1.f);
    gemm_m<<<dim3(16, 32), blk, 0, stream>>>(hidb, gfw2T, gfb2, x,
        out, nullptr, nullptr, nullptr, 4096, 1024, 1024, 0, 0, 1.f);
}

// Round 5
// 425.414 us; speedup vs baseline: 8.2796x; 1.1049x over previous
//
#include <hip/hip_runtime.h>
#include <math.h>

#define B_ 4
#define N_ 1024
#define C_ 1024
#define NH_ 16
#define HD_ 64
#define PP_ 128

typedef __bf16 bf16;
typedef __attribute__((ext_vector_type(8))) __bf16 bf16x8;
typedef __attribute__((ext_vector_type(4))) __bf16 bf16x4;
typedef __attribute__((ext_vector_type(4))) float f32x4;

#define MFMA_BF16(a, b, c) __builtin_amdgcn_mfma_f32_16x16x32_bf16((a), (b), (c), 0, 0, 0)

__device__ __forceinline__ float gelu_f(float x) {
    return 0.5f * x * (1.0f + erff(x * 0.70710678118654752f));
}

__device__ __forceinline__ void gload16(const void* g, void* l) {
    __builtin_amdgcn_global_load_lds(
        (const __attribute__((address_space(1))) void*)g,
        (__attribute__((address_space(3))) void*)l, 16, 0, 0);
}

// stage a 64-row x 128B tile into LDS with XOR-swizzle (source pre-swizzled,
// LDS dest linear for global_load_lds). 256 threads, 2 chunks each.
__device__ __forceinline__ void stage64_swz(const bf16* __restrict__ g, int pitchB,
                                            bf16* lds, int t) {
    #pragma unroll
    for (int r = 0; r < 2; ++r) {
        int i = r * 256 + t;
        int row = i >> 3, c = i & 7;
        const char* src = (const char*)g + (size_t)row * pitchB + ((c ^ (row & 7)) << 4);
        bf16* dst = lds + (size_t)(r * 256 + (t & 192)) * 8;   // wave-uniform base
        gload16(src, dst);
    }
}

__device__ __forceinline__ bf16x8 lds8_swz(const bf16* lds, int row, int colb) {
    return *reinterpret_cast<const bf16x8*>(
        (const char*)lds + row * 128 + (colb ^ ((row & 7) << 4)));
}

// ============ rope table ============
__global__ __launch_bounds__(256) void rope_tab_k(float2* __restrict__ rt)
{
    int g = blockIdx.x * 256 + threadIdx.x;   // 32768
    const int n = g >> 5, i = g & 31;
    const float inv = powf(10000.0f, -(float)(2 * i) / 64.0f);
    const float ang = (float)n * inv;
    rt[g] = make_float2(cosf(ang), sinf(ang));
}

// ============ rel table transpose ============
__global__ __launch_bounds__(256) void relT_k(const float* __restrict__ rel_table,
                                              float* __restrict__ relT)
{
    int g = blockIdx.x * 256 + threadIdx.x;
    if (g >= 16 * 3969) return;
    int h = g / 3969, idx = g - h * 3969;
    relT[g] = rel_table[idx * 16 + h];
}

// ============ transpose-cast fp32 W[K,N] -> bf16 Wt[N,K] (11 jobs) ============
struct TJobs {
    const float* src[11];
    bf16* dst[11];
    int K[11];
    int N[11];
};

__global__ __launch_bounds__(256) void tcast_k(TJobs J)
{
    const int j = blockIdx.z;
    const int Kd = J.K[j], Nd = J.N[j];
    const int n0 = blockIdx.x * 32, k0 = blockIdx.y * 32;
    if (n0 >= Nd || k0 >= Kd) return;
    __shared__ float tl[32][33];
    const int t = threadIdx.x, tx = t & 31, ty = t >> 5;
    const float* src = J.src[j];
    bf16* dst = J.dst[j];
    #pragma unroll
    for (int r = 0; r < 4; ++r) {
        int kk = ty + r * 8;
        tl[kk][tx] = src[(size_t)(k0 + kk) * Nd + n0 + tx];
    }
    __syncthreads();
    #pragma unroll
    for (int r = 0; r < 4; ++r) {
        int nn = ty + r * 8;
        dst[(size_t)(n0 + nn) * Kd + k0 + tx] = (bf16)tl[tx][nn];
    }
}

// ============ elementwise cast fp32 -> bf16 ============
__global__ __launch_bounds__(256) void cast_rm(const float* __restrict__ in,
                                               bf16* __restrict__ out, int n4)
{
    int g = blockIdx.x * 256 + threadIdx.x;
    if (g >= n4) return;
    float4 v = reinterpret_cast<const float4*>(in)[g];
    bf16x4 o = {(bf16)v.x, (bf16)v.y, (bf16)v.z, (bf16)v.w};
    reinterpret_cast<bf16x4*>(out)[g] = o;
}

// ============ MFMA GEMM, 2-phase double-buffered, fused epilogues ============
// C[M,N] = [A | A2][M,K] @ Bt[N,K]^T ; A covers k<K1 (pitch K1), A2 covers k>=K1.
// epi: 0=fp32 rm(+bias,+gelu,+resid) 1=bf16 rm(+bias,+gelu)
//      2=qkv split  3=head-major+rope  4=head-major transposed
//      5=fp32 out0 AND bf16 out1 (+bias)
__global__ __launch_bounds__(256) void gemm_m(
    const bf16* __restrict__ A, const bf16* __restrict__ A2,
    const bf16* __restrict__ Bt,
    const float* __restrict__ bias, const float* __restrict__ resid,
    void* __restrict__ out0, void* __restrict__ out1, void* __restrict__ out2,
    const float2* __restrict__ rtab,
    int M, int N, int K, int K1, int epi, int act_gelu, float scale)
{
    __shared__ bf16 As[2][128 * 32];
    __shared__ bf16 Bs[2][64 * 32];
    const int t = threadIdx.x;
    const int w = t >> 6, lane = t & 63;
    const int row0 = blockIdx.y * 128, col0 = blockIdx.x * 64;
    const int wm = w >> 1, wn = w & 1;
    const int K2 = K - K1;
    f32x4 acc[4][2];
    #pragma unroll
    for (int mi = 0; mi < 4; ++mi)
        #pragma unroll
        for (int ni = 0; ni < 2; ++ni)
            acc[mi][ni] = (f32x4){0.f, 0.f, 0.f, 0.f};

    #define STAGE_AB(k0, buf)                                                        \
        {                                                                            \
            _Pragma("unroll")                                                        \
            for (int r = 0; r < 2; ++r) {                                            \
                int c = r * 256 + t;                                                 \
                int arow = row0 + (c >> 2);                                          \
                const bf16* src = ((k0) < K1)                                        \
                    ? A + (size_t)arow * K1 + (k0) + (c & 3) * 8                     \
                    : A2 + (size_t)arow * K2 + ((k0) - K1) + (c & 3) * 8;            \
                gload16(src, As[buf] + (size_t)(r * 256 + w * 64) * 8);              \
            }                                                                        \
            const bf16* srcb = Bt + (size_t)(col0 + (t >> 2)) * K + (k0) + (t & 3) * 8; \
            gload16(srcb, Bs[buf] + (size_t)(w * 64) * 8);                           \
        }

    STAGE_AB(0, 0);
    __syncthreads();
    int cur = 0;
    const int nk = K >> 5;
    for (int kk = 0; kk < nk; ++kk) {
        if (kk + 1 < nk) STAGE_AB((kk + 1) * 32, cur ^ 1);
        bf16x8 af[4], bfv[2];
        #pragma unroll
        for (int mi = 0; mi < 4; ++mi)
            af[mi] = *reinterpret_cast<const bf16x8*>(
                As[cur] + (wm * 64 + mi * 16 + (lane & 15)) * 32 + (lane >> 4) * 8);
        #pragma unroll
        for (int ni = 0; ni < 2; ++ni)
            bfv[ni] = *reinterpret_cast<const bf16x8*>(
                Bs[cur] + (wn * 32 + ni * 16 + (lane & 15)) * 32 + (lane >> 4) * 8);
        #pragma unroll
        for (int mi = 0; mi < 4; ++mi)
            #pragma unroll
            for (int ni = 0; ni < 2; ++ni)
                acc[mi][ni] = MFMA_BF16(af[mi], bfv[ni], acc[mi][ni]);
        __syncthreads();
        cur ^= 1;
    }
    #undef STAGE_AB

    #pragma unroll
    for (int mi = 0; mi < 4; ++mi) {
        #pragma unroll
        for (int ni = 0; ni < 2; ++ni) {
            const int col = col0 + wn * 32 + ni * 16 + (lane & 15);
            if (epi <= 1 || epi == 5) {
                const float bv = bias ? bias[col] : 0.f;
                #pragma unroll
                for (int j = 0; j < 4; ++j) {
                    const int row = row0 + wm * 64 + mi * 16 + (lane >> 4) * 4 + j;
                    float v = acc[mi][ni][j] + bv;
                    if (act_gelu) v = gelu_f(v);
                    if (epi == 0) {
                        if (resid) v += resid[(size_t)row * N + col];
                        ((float*)out0)[(size_t)row * N + col] = v;
                    } else if (epi == 1) {
                        ((bf16*)out0)[(size_t)row * N + col] = (bf16)v;
                    } else {
                        ((float*)out0)[(size_t)row * N + col] = v;
                        ((bf16*)out1)[(size_t)row * N + col] = (bf16)v;
                    }
                }
            } else if (epi == 2) {
                const int reg = col >> 10;         // 0=q 1=k 2=v
                const int h = (col >> 6) & 15, d = col & 63;
                if (reg <= 1) {
                    bf16* dst = reg == 0 ? (bf16*)out0 : (bf16*)out1;
                    const float sc = reg == 0 ? scale : 1.0f;
                    #pragma unroll
                    for (int j = 0; j < 4; ++j) {
                        const int row = row0 + wm * 64 + mi * 16 + (lane >> 4) * 4 + j;
                        const int b = row >> 10, n = row & 1023;
                        float v = acc[mi][ni][j];
                        float pv = __shfl_xor(v, 1);
                        float2 cs = rtab[(n << 5) + (d >> 1)];
                        float o = (d & 1) == 0 ? v * cs.x - pv * cs.y
                                               : v * cs.x + pv * cs.y;
                        dst[((size_t)((b * 16 + h) * 1024 + n)) * 64 + d] = (bf16)(o * sc);
                    }
                } else {
                    bf16x4 o4;
                    #pragma unroll
                    for (int j = 0; j < 4; ++j) o4[j] = (bf16)acc[mi][ni][j];
                    const int row = row0 + wm * 64 + mi * 16 + (lane >> 4) * 4;
                    const int b = row >> 10, n = row & 1023;
                    *reinterpret_cast<bf16x4*>(
                        (bf16*)out2 + ((size_t)((b * 16 + h) * 64 + d)) * 1024 + n) = o4;
                }
            } else if (epi == 3) {
                const int h = (col >> 6) & 15, d = col & 63;
                #pragma unroll
                for (int j = 0; j < 4; ++j) {
                    const int row = row0 + wm * 64 + mi * 16 + (lane >> 4) * 4 + j;
                    const int b = row >> 10, n = row & 1023;
                    float v = acc[mi][ni][j];
                    float pv = __shfl_xor(v, 1);
                    float2 cs = rtab[(n << 5) + (d >> 1)];
                    float o = (d & 1) == 0 ? v * cs.x - pv * cs.y
                                           : v * cs.x + pv * cs.y;
                    ((bf16*)out0)[((size_t)((b * 16 + h) * 1024 + n)) * 64 + d] = (bf16)(o * scale);
                }
            } else {  // epi == 4: transposed head-major
                const int h = (col >> 6) & 15, d = col & 63;
                bf16x4 o4;
                #pragma unroll
                for (int j = 0; j < 4; ++j) o4[j] = (bf16)acc[mi][ni][j];
                const int row = row0 + wm * 64 + mi * 16 + (lane >> 4) * 4;
                const int b = row >> 10, n = row & 1023;
                *reinterpret_cast<bf16x4*>(
                    (bf16*)out0 + ((size_t)((b * 16 + h) * 64 + d)) * 1024 + n) = o4;
            }
        }
    }
}

// ============ XCD-aware block decomposition for attention ============
__device__ __forceinline__ void attn_bid(int bid, int& bh, int& r0t) {
    const int xcd = bid & 7, s = bid >> 3;
    bh = (s >> 4) * 8 + xcd;   // 0..63
    r0t = s & 15;
}

// ============ MFMA flash self-attention, 2-phase pipelined ============
__global__ __launch_bounds__(256) void attn_self_m(
    const bf16* __restrict__ qb, const bf16* __restrict__ kb, const bf16* __restrict__ vtb,
    const float* __restrict__ relT, bf16* __restrict__ sab)
{
    __shared__ bf16 Ks[2][64 * 64];
    __shared__ bf16 Vs[2][64 * 64];
    __shared__ bf16 Ps[64 * 72];
    __shared__ float relb[2][192];
    const int t = threadIdx.x, w = t >> 6, lane = t & 63;
    int bh, r0t;
    attn_bid(blockIdx.x, bh, r0t);
    const int b = bh >> 4, h = bh & 15, r0 = r0t * 64;
    const float* relTh = relT + h * 3969;
    const int y0 = r0 >> 5;

    stage64_swz(qb + ((size_t)bh * 1024 + r0) * 64, 128, Ks[0], t);
    __syncthreads();
    bf16x8 aq[2];
    {
        const int qr = w * 16 + (lane & 15);
        aq[0] = lds8_swz(Ks[0], qr, (lane >> 4) * 16);
        aq[1] = lds8_swz(Ks[0], qr, 64 + (lane >> 4) * 16);
    }
    __syncthreads();
    stage64_swz(kb + (size_t)bh * 65536, 128, Ks[0], t);
    stage64_swz(vtb + (size_t)bh * 65536, 2048, Vs[0], t);
    if (t < 192) {
        relb[0][t] = relTh[(y0 + 30 + (t >> 6)) * 63 + min(t & 63, 62)];
    }

    float m_run[4], l_run[4];
    f32x4 of[4];
    #pragma unroll
    for (int j = 0; j < 4; ++j) { m_run[j] = -3e38f; l_run[j] = 0.f; }
    #pragma unroll
    for (int dt = 0; dt < 4; ++dt) of[dt] = (f32x4){0.f, 0.f, 0.f, 0.f};

    const int qrow_lo = (lane >> 4) * 4;
    int dybase[4];
    #pragma unroll
    for (int j = 0; j < 4; ++j) {
        int qg = r0 + w * 16 + qrow_lo + j;
        dybase[j] = (((qg >> 5) - y0) + 1) * 64 + (qg & 31) + 31;
    }
    __syncthreads();

    int cur = 0;
    for (int mt = 0; mt < 16; ++mt) {
        if (mt < 15) {
            stage64_swz(kb + (size_t)bh * 65536 + (size_t)(mt + 1) * 64 * 64, 128, Ks[cur ^ 1], t);
            stage64_swz(vtb + (size_t)bh * 65536 + (size_t)(mt + 1) * 64, 2048, Vs[cur ^ 1], t);
            if (t < 192) {
                relb[cur ^ 1][t] = relTh[(y0 - 2 * (mt + 1) + 30 + (t >> 6)) * 63 + min(t & 63, 62)];
            }
        }
        f32x4 sf[4];
        __builtin_amdgcn_s_setprio(1);
        #pragma unroll
        for (int ct = 0; ct < 4; ++ct) {
            const int kr = ct * 16 + (lane & 15);
            f32x4 a = (f32x4){0.f, 0.f, 0.f, 0.f};
            a = MFMA_BF16(aq[0], lds8_swz(Ks[cur], kr, (lane >> 4) * 16), a);
            a = MFMA_BF16(aq[1], lds8_swz(Ks[cur], kr, 64 + (lane >> 4) * 16), a);
            sf[ct] = a;
        }
        __builtin_amdgcn_s_setprio(0);
        float p[4][4], mx[4];
        #pragma unroll
        for (int j = 0; j < 4; ++j) mx[j] = -3e38f;
        #pragma unroll
        for (int ct = 0; ct < 4; ++ct) {
            const int xm = (ct & 1) * 16 + (lane & 15);
            const int ro = (ct >> 1) * 64 + xm;
            #pragma unroll
            for (int j = 0; j < 4; ++j) {
                float s = sf[ct][j] + relb[cur][dybase[j] - ro];
                p[ct][j] = s;
                mx[j] = fmaxf(mx[j], s);
            }
        }
        #pragma unroll
        for (int d = 1; d < 16; d <<= 1)
            #pragma unroll
            for (int j = 0; j < 4; ++j) mx[j] = fmaxf(mx[j], __shfl_xor(mx[j], d));
        float alpha[4], rs[4];
        #pragma unroll
        for (int j = 0; j < 4; ++j) {
            float mn = fmaxf(m_run[j], mx[j]);
            alpha[j] = __expf(m_run[j] - mn);
            m_run[j] = mn;
            rs[j] = 0.f;
        }
        #pragma unroll
        for (int ct = 0; ct < 4; ++ct)
            #pragma unroll
            for (int j = 0; j < 4; ++j) {
                float e = __expf(p[ct][j] - m_run[j]);
                p[ct][j] = e;
                rs[j] += e;
            }
        #pragma unroll
        for (int d = 1; d < 16; d <<= 1)
            #pragma unroll
            for (int j = 0; j < 4; ++j) rs[j] += __shfl_xor(rs[j], d);
        #pragma unroll
        for (int j = 0; j < 4; ++j) l_run[j] = l_run[j] * alpha[j] + rs[j];
        #pragma unroll
        for (int dt = 0; dt < 4; ++dt)
            #pragma unroll
            for (int j = 0; j < 4; ++j) of[dt][j] *= alpha[j];
        #pragma unroll
        for (int ct = 0; ct < 4; ++ct)
            #pragma unroll
            for (int j = 0; j < 4; ++j)
                Ps[(w * 16 + qrow_lo + j) * 72 + ct * 16 + (lane & 15)] = (bf16)p[ct][j];
        asm volatile("s_waitcnt lgkmcnt(0)" ::: "memory");
        __builtin_amdgcn_sched_barrier(0);
        bf16x8 ap0 = *reinterpret_cast<const bf16x8*>(Ps + (w * 16 + (lane & 15)) * 72 + (lane >> 4) * 8);
        bf16x8 ap1 = *reinterpret_cast<const bf16x8*>(Ps + (w * 16 + (lane & 15)) * 72 + 32 + (lane >> 4) * 8);
        __builtin_amdgcn_s_setprio(1);
        #pragma unroll
        for (int dt = 0; dt < 4; ++dt) {
            const int vr = dt * 16 + (lane & 15);
            of[dt] = MFMA_BF16(ap0, lds8_swz(Vs[cur], vr, (lane >> 4) * 16), of[dt]);
            of[dt] = MFMA_BF16(ap1, lds8_swz(Vs[cur], vr, 64 + (lane >> 4) * 16), of[dt]);
        }
        __builtin_amdgcn_s_setprio(0);
        __syncthreads();
        cur ^= 1;
    }
    float inv[4];
    #pragma unroll
    for (int j = 0; j < 4; ++j) inv[j] = 1.f / l_run[j];
    #pragma unroll
    for (int dt = 0; dt < 4; ++dt)
        #pragma unroll
        for (int j = 0; j < 4; ++j)
            sab[((size_t)(b * N_ + r0 + w * 16 + qrow_lo + j)) * C_ + h * 64 + dt * 16 + (lane & 15)] =
                (bf16)(of[dt][j] * inv[j]);
}

// ============ MFMA flash cross-attention, 2-phase pipelined ============
__global__ __launch_bounds__(256) void attn_cross_m(
    const bf16* __restrict__ cq, const bf16* __restrict__ ck, const bf16* __restrict__ cvt,
    const float* __restrict__ dn, const float* __restrict__ ds, const float* __restrict__ gb,
    const float* __restrict__ rdb, bf16* __restrict__ cob)
{
    __shared__ bf16 Ks[2][64 * 64];
    __shared__ bf16 Vs[2][64 * 64];
    __shared__ bf16 Ps[64 * 72];
    __shared__ float4 dnms[2][64];
    const int t = threadIdx.x, w = t >> 6, lane = t & 63;
    int bh, r0t;
    attn_bid(blockIdx.x, bh, r0t);
    const int b = bh >> 4, h = bh & 15, r0 = r0t * 64;
    const size_t rowbase = (size_t)b * N_;
    const float rdbh = rdb[h];

    stage64_swz(cq + ((size_t)bh * 1024 + r0) * 64, 128, Ks[0], t);
    __syncthreads();
    bf16x8 aq[2];
    {
        const int qr = w * 16 + (lane & 15);
        aq[0] = lds8_swz(Ks[0], qr, (lane >> 4) * 16);
        aq[1] = lds8_swz(Ks[0], qr, 64 + (lane >> 4) * 16);
    }
    __syncthreads();
    stage64_swz(ck + (size_t)bh * 65536, 128, Ks[0], t);
    stage64_swz(cvt + (size_t)bh * 65536, 2048, Vs[0], t);
    if (t < 64) {
        float4 d4 = *reinterpret_cast<const float4*>(dn + (rowbase + t) * 4);
        dnms[0][t] = make_float4(d4.x, d4.y, d4.z, gb[(rowbase + t) * NH_ + h]);
    }

    const int qrow_lo = (lane >> 4) * 4;
    float dqx[4], dqy[4], dqz[4], dsr[4];
    #pragma unroll
    for (int j = 0; j < 4; ++j) {
        const size_t rg = rowbase + r0 + w * 16 + qrow_lo + j;
        dqx[j] = dn[rg * 4 + 0];
        dqy[j] = dn[rg * 4 + 1];
        dqz[j] = dn[rg * 4 + 2];
        dsr[j] = 1.0f + ds[rg * NH_ + h];
    }

    float m_run[4], l_run[4];
    f32x4 of[4];
    #pragma unroll
    for (int j = 0; j < 4; ++j) { m_run[j] = -3e38f; l_run[j] = 0.f; }
    #pragma unroll
    for (int dt = 0; dt < 4; ++dt) of[dt] = (f32x4){0.f, 0.f, 0.f, 0.f};
    __syncthreads();

    int cur = 0;
    for (int mt = 0; mt < 16; ++mt) {
        if (mt < 15) {
            stage64_swz(ck + (size_t)bh * 65536 + (size_t)(mt + 1) * 64 * 64, 128, Ks[cur ^ 1], t);
            stage64_swz(cvt + (size_t)bh * 65536 + (size_t)(mt + 1) * 64, 2048, Vs[cur ^ 1], t);
            if (t < 64) {
                float4 d4 = *reinterpret_cast<const float4*>(dn + (rowbase + (mt + 1) * 64 + t) * 4);
                dnms[cur ^ 1][t] = make_float4(d4.x, d4.y, d4.z, gb[(rowbase + (mt + 1) * 64 + t) * NH_ + h]);
            }
        }
        f32x4 sf[4];
        __builtin_amdgcn_s_setprio(1);
        #pragma unroll
        for (int ct = 0; ct < 4; ++ct) {
            const int kr = ct * 16 + (lane & 15);
            f32x4 a = (f32x4){0.f, 0.f, 0.f, 0.f};
            a = MFMA_BF16(aq[0], lds8_swz(Ks[cur], kr, (lane >> 4) * 16), a);
            a = MFMA_BF16(aq[1], lds8_swz(Ks[cur], kr, 64 + (lane >> 4) * 16), a);
            sf[ct] = a;
        }
        __builtin_amdgcn_s_setprio(0);
        float p[4][4], mx[4];
        #pragma unroll
        for (int j = 0; j < 4; ++j) mx[j] = -3e38f;
        #pragma unroll
        for (int ct = 0; ct < 4; ++ct) {
            const float4 dm = dnms[cur][ct * 16 + (lane & 15)];
            #pragma unroll
            for (int j = 0; j < 4; ++j) {
                float sim = dqx[j] * dm.x + dqy[j] * dm.y + dqz[j] * dm.z;
                float s = (sf[ct][j] + sim * rdbh) * dsr[j] + dm.w;
                p[ct][j] = s;
                mx[j] = fmaxf(mx[j], s);
            }
        }
        #pragma unroll
        for (int d = 1; d < 16; d <<= 1)
            #pragma unroll
            for (int j = 0; j < 4; ++j) mx[j] = fmaxf(mx[j], __shfl_xor(mx[j], d));
        float alpha[4], rs[4];
        #pragma unroll
        for (int j = 0; j < 4; ++j) {
            float mn = fmaxf(m_run[j], mx[j]);
            alpha[j] = __expf(m_run[j] - mn);
            m_run[j] = mn;
            rs[j] = 0.f;
        }
        #pragma unroll
        for (int ct = 0; ct < 4; ++ct)
            #pragma unroll
            for (int j = 0; j < 4; ++j) {
                float e = __expf(p[ct][j] - m_run[j]);
                p[ct][j] = e;
                rs[j] += e;
            }
        #pragma unroll
        for (int d = 1; d < 16; d <<= 1)
            #pragma unroll
            for (int j = 0; j < 4; ++j) rs[j] += __shfl_xor(rs[j], d);
        #pragma unroll
        for (int j = 0; j < 4; ++j) l_run[j] = l_run[j] * alpha[j] + rs[j];
        #pragma unroll
        for (int dt = 0; dt < 4; ++dt)
            #pragma unroll
            for (int j = 0; j < 4; ++j) of[dt][j] *= alpha[j];
        #pragma unroll
        for (int ct = 0; ct < 4; ++ct)
            #pragma unroll
            for (int j = 0; j < 4; ++j)
                Ps[(w * 16 + qrow_lo + j) * 72 + ct * 16 + (lane & 15)] = (bf16)p[ct][j];
        asm volatile("s_waitcnt lgkmcnt(0)" ::: "memory");
        __builtin_amdgcn_sched_barrier(0);
        bf16x8 ap0 = *reinterpret_cast<const bf16x8*>(Ps + (w * 16 + (lane & 15)) * 72 + (lane >> 4) * 8);
        bf16x8 ap1 = *reinterpret_cast<const bf16x8*>(Ps + (w * 16 + (lane & 15)) * 72 + 32 + (lane >> 4) * 8);
        __builtin_amdgcn_s_setprio(1);
        #pragma unroll
        for (int dt = 0; dt < 4; ++dt) {
            const int vr = dt * 16 + (lane & 15);
            of[dt] = MFMA_BF16(ap0, lds8_swz(Vs[cur], vr, (lane >> 4) * 16), of[dt]);
            of[dt] = MFMA_BF16(ap1, lds8_swz(Vs[cur], vr, 64 + (lane >> 4) * 16), of[dt]);
        }
        __builtin_amdgcn_s_setprio(0);
        __syncthreads();
        cur ^= 1;
    }
    float inv[4];
    #pragma unroll
    for (int j = 0; j < 4; ++j) inv[j] = 1.f / l_run[j];
    #pragma unroll
    for (int dt = 0; dt < 4; ++dt)
        #pragma unroll
        for (int j = 0; j < 4; ++j)
            cob[(rowbase + r0 + w * 16 + qrow_lo + j) * C_ + h * 64 + dt * 16 + (lane & 15)] =
                (bf16)(of[dt][j] * inv[j]);
}

// ============ plucker layer1 (K=6) + ds MLP + dn; 4 rows per block ============
__global__ __launch_bounds__(256) void plucker1_k(
    const float* __restrict__ pl,
    const float* __restrict__ w1, const float* __restrict__ b1,
    const float* __restrict__ dw1, const float* __restrict__ db1,
    const float* __restrict__ dw2, const float* __restrict__ db2,
    bf16* __restrict__ h1b, float* __restrict__ ds, float* __restrict__ dn)
{
    const int t = threadIdx.x;
    __shared__ float plr[6];
    __shared__ float dh[64];
    #pragma unroll 1
    for (int rr = 0; rr < 4; ++rr) {
        const int row = blockIdx.x * 4 + rr;
        if (t < 6) plr[t] = pl[(size_t)row * 6 + t];
        __syncthreads();
        {
            float a = b1[t];
            #pragma unroll
            for (int j = 0; j < 6; ++j) a = fmaf(plr[j], w1[j * 256 + t], a);
            h1b[(size_t)row * 256 + t] = (bf16)gelu_f(a);
        }
        if (t < 64) {
            float d = db1[t];
            #pragma unroll
            for (int j = 0; j < 6; ++j) d = fmaf(plr[j], dw1[j * 64 + t], d);
            dh[t] = gelu_f(d);
        }
        if (t == 0) {
            float x = plr[0], y = plr[1], z = plr[2];
            float nrm = fmaxf(sqrtf(x * x + y * y + z * z), 1e-12f);
            dn[(size_t)row * 4 + 0] = x / nrm;
            dn[(size_t)row * 4 + 1] = y / nrm;
            dn[(size_t)row * 4 + 2] = z / nrm;
            dn[(size_t)row * 4 + 3] = 0.f;
        }
        __syncthreads();
        if (t < 16) {
            float d = db2[t];
            #pragma unroll 8
            for (int j = 0; j < 64; ++j) d = fmaf(dh[j], dw2[j * 16 + t], d);
            ds[(size_t)row * 16 + t] = tanhf(d);
        }
        __syncthreads();
    }
}

// ============ spatial diffs -> bf16 ============
__global__ __launch_bounds__(256) void sd_k(const float* __restrict__ pp, bf16* __restrict__ sd)
{
    int g = blockIdx.x * 256 + threadIdx.x;
    if (g >= B_ * N_ * PP_) return;
    const int c = g & 127;
    const int rown = g >> 7;
    const int n = rown & (N_ - 1);
    const int xx = n & 31, yy = (n >> 5) & 31;
    const float cur = pp[g];
    const float hd = (xx < 31) ? fabsf(pp[g + PP_] - cur) : 0.f;
    const float vd = (yy < 31) ? fabsf(pp[g + 32 * PP_] - cur) : 0.f;
    sd[(size_t)rown * 256 + c] = (bf16)hd;
    sd[(size_t)rown * 256 + 128 + c] = (bf16)vd;
}

// ============ gb layer2: (4096,512)bf16 @ w2(512,16) -> tanh -> fp32 ============
__global__ __launch_bounds__(256) void gb2_k(
    const bf16* __restrict__ h, const float* __restrict__ w2,
    const float* __restrict__ b2, float* __restrict__ gbv)
{
    __shared__ float w2s[512 * 16];
    const int t = threadIdx.x;
    for (int i = t; i < 8192; i += 256) w2s[i] = w2[i];
    __syncthreads();
    const int row = blockIdx.x * 16 + (t >> 4);
    const int col = t & 15;
    const bf16* hr = h + (size_t)row * 512;
    float acc = b2[col];
    #pragma unroll 8
    for (int j = 0; j < 512; ++j)
        acc = fmaf((float)hr[j], w2s[j * 16 + col], acc);
    gbv[(size_t)row * 16 + col] = tanhf(acc);
}

extern "C" void kernel_launch(void* const* d_in, const int* in_sizes, int n_in,
                              void* d_out, int out_size, void* d_ws, size_t ws_size,
                              hipStream_t stream)
{
    const float* x     = (const float*)d_in[0];
    const float* pl    = (const float*)d_in[1];
    const float* w_qkv = (const float*)d_in[2];
    const float* w_sp  = (const float*)d_in[3];
    const float* b_sp  = (const float*)d_in[4];
    const float* pl_w1 = (const float*)d_in[5];
    const float* pl_b1 = (const float*)d_in[6];
    const float* pl_w2 = (const float*)d_in[7];
    const float* pl_b2 = (const float*)d_in[8];
    const float* pl_w3 = (const float*)d_in[9];
    const float* pl_b3 = (const float*)d_in[10];
    const float* w_cq  = (const float*)d_in[11];
    const float* w_pk  = (const float*)d_in[12];
    const float* w_pv  = (const float*)d_in[13];
    const float* w_cp  = (const float*)d_in[14];
    const float* b_cp  = (const float*)d_in[15];
    const float* rdb   = (const float*)d_in[16];
    const float* ds_w1 = (const float*)d_in[17];
    const float* ds_b1 = (const float*)d_in[18];
    const float* ds_w2 = (const float*)d_in[19];
    const float* ds_b2 = (const float*)d_in[20];
    const float* gb_w1 = (const float*)d_in[21];
    const float* gb_b1 = (const float*)d_in[22];
    const float* gb_w2 = (const float*)d_in[23];
    const float* gb_b2 = (const float*)d_in[24];
    const float* rel_t = (const float*)d_in[25];
    const float* gfw1  = (const float*)d_in[26];
    const float* gfb1  = (const float*)d_in[27];
    const float* gfw2  = (const float*)d_in[28];
    const float* gfb2  = (const float*)d_in[29];

    char* W = (char*)d_ws;
    float* out = (float*)d_out;
    const size_t MB = 1ull << 20;
    const size_t KB = 1024;

    bf16* qb     = (bf16*)(W + 0);           // 8MB ; cqb reuses
    bf16* kb     = (bf16*)(W + 8 * MB);      // 8MB ; ckb reuses
    bf16* vtb    = (bf16*)(W + 16 * MB);     // 8MB ; cvtb reuses
    bf16* cqb    = qb;
    bf16* ckb    = kb;
    bf16* cvtb   = vtb;
    bf16* xb     = (bf16*)(W + 24 * MB);     // 8MB
    bf16* wqkvT  = (bf16*)(W + 32 * MB);     // 6MB
    bf16* wspT   = (bf16*)(W + 38 * MB);     // 2MB
    bf16* wcqT   = (bf16*)(W + 40 * MB);     // 2MB
    bf16* wpkT   = (bf16*)(W + 42 * MB);               // 256KB
    bf16* wpvT   = (bf16*)(W + 42 * MB + 256 * KB);    // 256KB
    bf16* wcpT   = (bf16*)(W + 43 * MB);     // 2MB
    bf16* gfw1T  = (bf16*)(W + 45 * MB);     // 2.25MB
    bf16* gfw2T  = (bf16*)(W + 48 * MB);     // 2MB
    bf16* plw2T  = (bf16*)(W + 50 * MB);               // 64KB  [128][256]
    bf16* plw3T  = (bf16*)(W + 50 * MB + 64 * KB);     // 32KB  [128][128]
    bf16* gbw1T  = (bf16*)(W + 50 * MB + 128 * KB);    // 256KB [512][256]
    bf16* sab    = (bf16*)(W + 51 * MB);     // 8MB ; cob reuses
    bf16* cob    = sab;
    bf16* sapb   = (bf16*)(W + 59 * MB);     // 8MB ; copb reuses
    bf16* copb   = sapb;
    float* pp    = (float*)(W + 67 * MB);    // 2MB
    bf16* ppb    = (bf16*)(W + 69 * MB);     // 1MB
    bf16* sdb16  = (bf16*)(W + 70 * MB);     // 2MB
    bf16* h1b    = (bf16*)(W + 72 * MB);     // 2MB
    bf16* h2b    = (bf16*)(W + 74 * MB);     // 1MB
    bf16* gbh    = (bf16*)(W + 75 * MB);     // 4MB
    float* dsb   = (float*)(W + 79 * MB);              // 256KB
    float* dnb   = (float*)(W + 79 * MB + 256 * KB);   // 64KB
    float* gbb   = (float*)(W + 79 * MB + 320 * KB);   // 256KB
    float2* rtab = (float2*)(W + 80 * MB);             // 256KB
    float* relTb = (float*)(W + 80 * MB + 256 * KB);   // 254KB
    bf16* hidb   = (bf16*)(W + 81 * MB);     // 8MB  -> 89MB total

    const dim3 blk(256);

    TJobs J;
    J.src[0] = w_qkv; J.dst[0] = wqkvT; J.K[0] = 1024; J.N[0] = 3072;
    J.src[1] = w_sp;  J.dst[1] = wspT;  J.K[1] = 1024; J.N[1] = 1024;
    J.src[2] = w_cq;  J.dst[2] = wcqT;  J.K[2] = 1024; J.N[2] = 1024;
    J.src[3] = w_pk;  J.dst[3] = wpkT;  J.K[3] = 128;  J.N[3] = 1024;
    J.src[4] = w_pv;  J.dst[4] = wpvT;  J.K[4] = 128;  J.N[4] = 1024;
    J.src[5] = w_cp;  J.dst[5] = wcpT;  J.K[5] = 1024; J.N[5] = 1024;
    J.src[6] = gfw1;  J.dst[6] = gfw1T; J.K[6] = 1152; J.N[6] = 1024;
    J.src[7] = gfw2;  J.dst[7] = gfw2T; J.K[7] = 1024; J.N[7] = 1024;
    J.src[8] = pl_w2; J.dst[8] = plw2T; J.K[8] = 256;  J.N[8] = 128;
    J.src[9] = pl_w3; J.dst[9] = plw3T; J.K[9] = 128;  J.N[9] = 128;
    J.src[10]= gb_w1; J.dst[10]= gbw1T; J.K[10]= 256;  J.N[10]= 512;
    tcast_k<<<dim3(96, 36, 11), blk, 0, stream>>>(J);
    cast_rm<<<4096, blk, 0, stream>>>(x, xb, 1048576);
    rope_tab_k<<<128, blk, 0, stream>>>(rtab);
    relT_k<<<249, blk, 0, stream>>>(rel_t, relTb);

    // qkv GEMM: fused rope + scale + bf16 head-major q,k + transposed v
    gemm_m<<<dim3(48, 32), blk, 0, stream>>>(xb, nullptr, wqkvT, nullptr, nullptr,
        qb, kb, vtb, rtab, 4096, 3072, 1024, 1024, 2, 0, 0.125f);
    // self attention
    attn_self_m<<<1024, blk, 0, stream>>>(qb, kb, vtb, relTb, sab);
    // self proj -> bf16 row-major
    gemm_m<<<dim3(16, 32), blk, 0, stream>>>(sab, nullptr, wspT, b_sp, nullptr,
        sapb, nullptr, nullptr, nullptr, 4096, 1024, 1024, 1024, 1, 0, 1.f);
    // plucker layer1 + ds MLP + dn
    plucker1_k<<<1024, blk, 0, stream>>>(pl, pl_w1, pl_b1,
                                         ds_w1, ds_b1, ds_w2, ds_b2, h1b, dsb, dnb);
    // plucker layer2 (gelu) and layer3 (fp32 pp + bf16 ppb)
    gemm_m<<<dim3(2, 32), blk, 0, stream>>>(h1b, nullptr, plw2T, pl_b2, nullptr,
        h2b, nullptr, nullptr, nullptr, 4096, 128, 256, 256, 1, 1, 1.f);
    gemm_m<<<dim3(2, 32), blk, 0, stream>>>(h2b, nullptr, plw3T, pl_b3, nullptr,
        pp, ppb, nullptr, nullptr, 4096, 128, 128, 128, 5, 0, 1.f);
    // spatial diffs -> bf16, gb layer1 GEMM (gelu), gb layer2 (tanh)
    sd_k<<<2048, blk, 0, stream>>>(pp, sdb16);
    gemm_m<<<dim3(8, 32), blk, 0, stream>>>(sdb16, nullptr, gbw1T, gb_b1, nullptr,
        gbh, nullptr, nullptr, nullptr, 4096, 512, 256, 256, 1, 1, 1.f);
    gb2_k<<<256, blk, 0, stream>>>(gbh, gb_w2, gb_b2, gbb);
    // cq / ck (rope+head-major) / cv (transposed head-major)
    gemm_m<<<dim3(16, 32), blk, 0, stream>>>(sapb, nullptr, wcqT, nullptr, nullptr,
        cqb, nullptr, nullptr, rtab, 4096, 1024, 1024, 1024, 3, 0, 0.125f);
    gemm_m<<<dim3(16, 32), blk, 0, stream>>>(ppb, nullptr, wpkT, nullptr, nullptr,
        ckb, nullptr, nullptr, rtab, 4096, 1024, 128, 128, 3, 0, 1.0f);
    gemm_m<<<dim3(16, 32), blk, 0, stream>>>(ppb, nullptr, wpvT, nullptr, nullptr,
        cvtb, nullptr, nullptr, nullptr, 4096, 1024, 128, 128, 4, 0, 1.f);
    // cross attention
    attn_cross_m<<<1024, blk, 0, stream>>>(cqb, ckb, cvtb, dnb, dsb, gbb, rdb, cob);
    // cross proj
    gemm_m<<<dim3(16, 32), blk, 0, stream>>>(cob, nullptr, wcpT, b_cp, nullptr,
        copb, nullptr, nullptr, nullptr, 4096, 1024, 1024, 1024, 1, 0, 1.f);
    // gfe1: split-A [co_p | pp] @ gfw1 (gelu)
    gemm_m<<<dim3(16, 32), blk, 0, stream>>>(copb, ppb, gfw1T, gfb1, nullptr,
        hidb, nullptr, nullptr, nullptr, 4096, 1024, 1152, 1024, 1, 1, 1.f);
    // gfe2 + bias + residual -> fp32 out
    gemm_m<<<dim3(16, 32), blk, 0, stream>>>(hidb, nullptr, gfw2T, gfb2, x,
        out, nullptr, nullptr, nullptr, 4096, 1024, 1024, 1024, 0, 0, 1.f);
}